// Round 1
// baseline (918.246 us; speedup 1.0000x reference)
//
#include <hip/hip_runtime.h>
#include <math.h>

#define NN 50000
#define NE 800000
#define IN_DIM 128
#define HID 256
#define OUT_DIM 40
#define BN_EPS 1e-5f

// ---------------- graph preprocessing ----------------

__global__ void k_hist(const int* __restrict__ row, const int* __restrict__ col,
                       unsigned* __restrict__ degcnt, unsigned* __restrict__ rowcnt) {
    for (int e = blockIdx.x * blockDim.x + threadIdx.x; e < NE; e += gridDim.x * blockDim.x) {
        atomicAdd(&rowcnt[row[e]], 1u);
        atomicAdd(&degcnt[col[e]], 1u);
    }
}

__global__ void k_dinv(const unsigned* __restrict__ degcnt, float* __restrict__ dinv) {
    int i = blockIdx.x * blockDim.x + threadIdx.x;
    if (i < NN) dinv[i] = rsqrtf((float)(degcnt[i] + 1u));  // +1 self loop
}

// block-local exclusive scan (256/block), Hillis-Steele
__global__ void k_scan_block(const unsigned* __restrict__ cnt, unsigned* __restrict__ excl,
                             unsigned* __restrict__ partials) {
    __shared__ unsigned s[256];
    int t = threadIdx.x;
    int i = blockIdx.x * 256 + t;
    unsigned v = (i < NN) ? cnt[i] : 0u;
    s[t] = v;
    __syncthreads();
    for (int off = 1; off < 256; off <<= 1) {
        unsigned x = (t >= off) ? s[t - off] : 0u;
        __syncthreads();
        s[t] += x;
        __syncthreads();
    }
    if (i < NN) excl[i] = s[t] - v;
    if (t == 255) partials[blockIdx.x] = s[255];
}

__global__ void k_scan_partials(unsigned* __restrict__ partials, int n) {
    __shared__ unsigned s[256];
    int t = threadIdx.x;
    unsigned v = (t < n) ? partials[t] : 0u;
    s[t] = v;
    __syncthreads();
    for (int off = 1; off < 256; off <<= 1) {
        unsigned x = (t >= off) ? s[t - off] : 0u;
        __syncthreads();
        s[t] += x;
        __syncthreads();
    }
    if (t < n) partials[t] = s[t] - v;
}

__global__ void k_scan_add(unsigned* __restrict__ rowptr, const unsigned* __restrict__ partials,
                           unsigned* __restrict__ cursor) {
    int i = blockIdx.x * blockDim.x + threadIdx.x;
    if (i < NN) {
        unsigned p = rowptr[i] + partials[i >> 8];
        rowptr[i] = p;
        cursor[i] = p;
    }
    if (i == 0) rowptr[NN] = NE;
}

__global__ void k_fill(const int* __restrict__ row, const int* __restrict__ col,
                       unsigned* __restrict__ cursor, int* __restrict__ colidx) {
    for (int e = blockIdx.x * blockDim.x + threadIdx.x; e < NE; e += gridDim.x * blockDim.x) {
        int r = row[e];
        unsigned p = atomicAdd(&cursor[r], 1u);
        colidx[p] = col[e];
    }
}

// ---------------- GEMM: Y[N x 256] = A[N x K] @ W[K x 256] ----------------
// 128 threads, 8 rows/block, 2 cols/thread.
template <int K>
__global__ __launch_bounds__(128) void k_gemm_hid(const float* __restrict__ A,
                                                  const float* __restrict__ W,
                                                  float* __restrict__ Y) {
    __shared__ float sh[8 * K];
    int t = threadIdx.x;
    long r0 = (long)blockIdx.x * 8;
    for (int idx = t; idx < 8 * K; idx += 128) {
        int rr = idx / K, kk = idx % K;
        sh[idx] = A[(r0 + rr) * K + kk];
    }
    __syncthreads();
    float acc0[8], acc1[8];
#pragma unroll
    for (int i = 0; i < 8; i++) { acc0[i] = 0.f; acc1[i] = 0.f; }
    const float* Wt = W + t;
#pragma unroll 4
    for (int k = 0; k < K; k++) {
        float w0 = Wt[(size_t)k * 256];
        float w1 = Wt[(size_t)k * 256 + 128];
#pragma unroll
        for (int i = 0; i < 8; i++) {
            float a = sh[i * K + k];
            acc0[i] += a * w0;
            acc1[i] += a * w1;
        }
    }
#pragma unroll
    for (int i = 0; i < 8; i++) {
        Y[(r0 + i) * 256 + t] = acc0[i];
        Y[(r0 + i) * 256 + t + 128] = acc1[i];
    }
}

// Y[N x 40] = A[N x 256] @ W[256 x 40]; 320 threads = 8 rows x 40 cols
__global__ __launch_bounds__(320) void k_gemm_out(const float* __restrict__ A,
                                                  const float* __restrict__ W,
                                                  float* __restrict__ Y) {
    __shared__ float sh[8 * 256];
    int t = threadIdx.x;
    long r0 = (long)blockIdx.x * 8;
    for (int idx = t; idx < 2048; idx += 320) sh[idx] = A[r0 * 256 + idx];
    __syncthreads();
    int lr = t / 40, lc = t % 40;
    float acc = 0.f;
#pragma unroll 4
    for (int k = 0; k < 256; k++) acc += sh[lr * 256 + k] * W[k * 40 + lc];
    Y[(r0 + lr) * 40 + lc] = acc;
}

// ---------------- aggregation ----------------
// H[r] = dinv[r] * ( sum_{c in N(r)} dinv[c]*Y[c] + dinv[r]*Y[r] ) + bias
__global__ __launch_bounds__(64) void k_agg_hid(const float* __restrict__ Y,
                                                const unsigned* __restrict__ rowptr,
                                                const int* __restrict__ colidx,
                                                const float* __restrict__ dinv,
                                                const float* __restrict__ bias,
                                                float* __restrict__ H) {
    int r = blockIdx.x;
    int t = threadIdx.x;  // 64 threads x float4 = 256 floats
    const float4* Yv = (const float4*)Y;
    float dr = dinv[r];
    float4 y = Yv[(size_t)r * 64 + t];
    float ax = dr * y.x, ay = dr * y.y, az = dr * y.z, aw = dr * y.w;
    unsigned e0 = rowptr[r], e1 = rowptr[r + 1];
    for (unsigned e = e0; e < e1; e++) {
        int c = colidx[e];
        float dc = dinv[c];
        float4 v = Yv[(size_t)c * 64 + t];
        ax += dc * v.x; ay += dc * v.y; az += dc * v.z; aw += dc * v.w;
    }
    float4 b = ((const float4*)bias)[t];
    float4 o;
    o.x = dr * ax + b.x; o.y = dr * ay + b.y; o.z = dr * az + b.z; o.w = dr * aw + b.w;
    ((float4*)H)[(size_t)r * 64 + t] = o;
}

__global__ __launch_bounds__(64) void k_agg_out(const float* __restrict__ Y,
                                                const unsigned* __restrict__ rowptr,
                                                const int* __restrict__ colidx,
                                                const float* __restrict__ dinv,
                                                const float* __restrict__ bias,
                                                float* __restrict__ H) {
    int r = blockIdx.x;
    int t = threadIdx.x;
    if (t >= OUT_DIM) return;
    float dr = dinv[r];
    float acc = dr * Y[(size_t)r * OUT_DIM + t];
    unsigned e0 = rowptr[r], e1 = rowptr[r + 1];
    for (unsigned e = e0; e < e1; e++) {
        int c = colidx[e];
        acc += dinv[c] * Y[(size_t)c * OUT_DIM + t];
    }
    H[(size_t)r * OUT_DIM + t] = dr * acc + bias[t];
}

// ---------------- BatchNorm ----------------
// bn layout: [0:256) sum, [256:512) sumsq, [512:768) scale, [768:1024) shift
__global__ __launch_bounds__(256) void k_bn_stats(const float* __restrict__ H, float* __restrict__ bn) {
    int t = threadIdx.x;
    int b = blockIdx.x;
    int rows_per = (NN + gridDim.x - 1) / gridDim.x;
    int r0 = b * rows_per;
    int r1 = r0 + rows_per; if (r1 > NN) r1 = NN;
    float s = 0.f, sq = 0.f;
    for (int r = r0; r < r1; r++) {
        float v = H[(size_t)r * 256 + t];
        s += v; sq += v * v;
    }
    atomicAdd(&bn[t], s);
    atomicAdd(&bn[256 + t], sq);
}

__global__ void k_bn_final(float* __restrict__ bn, const float* __restrict__ gamma,
                           const float* __restrict__ beta) {
    int t = threadIdx.x;
    float mu = bn[t] * (1.f / NN);
    float var = bn[256 + t] * (1.f / NN) - mu * mu;
    float rstd = rsqrtf(var + BN_EPS);
    float g = gamma[t] * rstd;
    bn[512 + t] = g;
    bn[768 + t] = beta[t] - mu * g;
}

__global__ __launch_bounds__(256) void k_bn_apply(float* __restrict__ H, const float* __restrict__ bn) {
    size_t i = (size_t)blockIdx.x * blockDim.x + threadIdx.x;  // over N*256/4 float4s
    float4 v = ((float4*)H)[i];
    int c4 = (int)(i & 63);
    float4 sc = ((const float4*)(bn + 512))[c4];
    float4 sf = ((const float4*)(bn + 768))[c4];
    v.x = fmaxf(v.x * sc.x + sf.x, 0.f);
    v.y = fmaxf(v.y * sc.y + sf.y, 0.f);
    v.z = fmaxf(v.z * sc.z + sf.z, 0.f);
    v.w = fmaxf(v.w * sc.w + sf.w, 0.f);
    ((float4*)H)[i] = v;
}

// ---------------- log_softmax ----------------
__global__ __launch_bounds__(256) void k_lsm(const float* __restrict__ H, float* __restrict__ out) {
    int r = blockIdx.x * blockDim.x + threadIdx.x;
    if (r >= NN) return;
    const float* p = H + (size_t)r * OUT_DIM;
    float m = -1e30f;
#pragma unroll
    for (int j = 0; j < OUT_DIM; j++) m = fmaxf(m, p[j]);
    float s = 0.f;
#pragma unroll
    for (int j = 0; j < OUT_DIM; j++) s += expf(p[j] - m);
    float ls = logf(s) + m;
    float* o = out + (size_t)r * OUT_DIM;
#pragma unroll
    for (int j = 0; j < OUT_DIM; j++) o[j] = p[j] - ls;
}

// ---------------- launch ----------------

extern "C" void kernel_launch(void* const* d_in, const int* in_sizes, int n_in,
                              void* d_out, int out_size, void* d_ws, size_t ws_size,
                              hipStream_t stream) {
    const float* x     = (const float*)d_in[0];
    const int*   erow  = (const int*)d_in[1];            // edge_index[0]
    const int*   ecol  = ((const int*)d_in[1]) + NE;     // edge_index[1]
    const float* W1    = (const float*)d_in[2];
    const float* b1    = (const float*)d_in[3];
    const float* W2    = (const float*)d_in[4];
    const float* b2    = (const float*)d_in[5];
    const float* W3    = (const float*)d_in[6];
    const float* b3    = (const float*)d_in[7];
    const float* gamma = (const float*)d_in[8];
    const float* beta  = (const float*)d_in[9];
    float* out = (float*)d_out;

    char* ws = (char*)d_ws;
    size_t off = 0;
    auto alloc = [&](size_t bytes) -> void* {
        void* p = ws + off;
        off = (off + bytes + 255) & ~(size_t)255;
        return p;
    };
    unsigned* degcnt   = (unsigned*)alloc(NN * 4);
    float*    dinv     = (float*)alloc(NN * 4);
    unsigned* rowcnt   = (unsigned*)alloc(NN * 4);
    unsigned* rowptr   = (unsigned*)alloc((NN + 1) * 4);
    unsigned* cursor   = (unsigned*)alloc(NN * 4);
    unsigned* partials = (unsigned*)alloc(256 * 4);
    int*      colidx   = (int*)alloc((size_t)NE * 4);
    float*    bn       = (float*)alloc(1024 * 4);
    float*    Y        = (float*)alloc((size_t)NN * HID * 4);
    float*    H        = (float*)alloc((size_t)NN * HID * 4);

    const int nscan = (NN + 255) / 256;  // 196

    // --- graph preprocessing ---
    hipMemsetAsync(degcnt, 0, NN * 4, stream);
    hipMemsetAsync(rowcnt, 0, NN * 4, stream);
    k_hist<<<1024, 256, 0, stream>>>(erow, ecol, degcnt, rowcnt);
    k_dinv<<<nscan, 256, 0, stream>>>(degcnt, dinv);
    k_scan_block<<<nscan, 256, 0, stream>>>(rowcnt, rowptr, partials);
    k_scan_partials<<<1, 256, 0, stream>>>(partials, nscan);
    k_scan_add<<<nscan, 256, 0, stream>>>(rowptr, partials, cursor);
    k_fill<<<1024, 256, 0, stream>>>(erow, ecol, cursor, colidx);

    // --- layer 1: conv(x, W1, b1) -> BN -> ReLU ---
    k_gemm_hid<IN_DIM><<<NN / 8, 128, 0, stream>>>(x, W1, Y);
    k_agg_hid<<<NN, 64, 0, stream>>>(Y, rowptr, colidx, dinv, b1, H);
    hipMemsetAsync(bn, 0, 512 * 4, stream);
    k_bn_stats<<<256, 256, 0, stream>>>(H, bn);
    k_bn_final<<<1, 256, 0, stream>>>(bn, gamma, beta);
    k_bn_apply<<<(NN * HID / 4) / 256, 256, 0, stream>>>(H, bn);

    // --- layer 2: conv(H, W2, b2) -> BN -> ReLU ---
    k_gemm_hid<HID><<<NN / 8, 128, 0, stream>>>(H, W2, Y);
    k_agg_hid<<<NN, 64, 0, stream>>>(Y, rowptr, colidx, dinv, b2, H);
    hipMemsetAsync(bn, 0, 512 * 4, stream);
    k_bn_stats<<<256, 256, 0, stream>>>(H, bn);
    k_bn_final<<<1, 256, 0, stream>>>(bn, gamma, beta);
    k_bn_apply<<<(NN * HID / 4) / 256, 256, 0, stream>>>(H, bn);

    // --- layer 3: conv(H, W3, b3) -> log_softmax ---
    k_gemm_out<<<NN / 8, 320, 0, stream>>>(H, W3, Y);
    k_agg_out<<<NN, 64, 0, stream>>>(Y, rowptr, colidx, dinv, b3, H);
    k_lsm<<<(NN + 255) / 256, 256, 0, stream>>>(H, out);
}

// Round 2
// 676.117 us; speedup vs baseline: 1.3581x; 1.3581x over previous
//
#include <hip/hip_runtime.h>
#include <math.h>

#define NN 50000
#define NE 800000
#define IN_DIM 128
#define HID 256
#define OUT_DIM 40
#define BN_EPS 1e-5f

typedef __attribute__((ext_vector_type(8))) short short8;
typedef __attribute__((ext_vector_type(4))) float f32x4;

__device__ __forceinline__ ushort f2bf(float f) {
    union { float f; unsigned u; } v; v.f = f;
    unsigned r = v.u + 0x7fffu + ((v.u >> 16) & 1u);
    return (ushort)(r >> 16);
}
__device__ __forceinline__ float bflo(unsigned u) {  // low bf16 of a u32
    union { unsigned a; float f; } v; v.a = u << 16; return v.f;
}
__device__ __forceinline__ float bfhi(unsigned u) {  // high bf16 of a u32
    union { unsigned a; float f; } v; v.a = u & 0xffff0000u; return v.f;
}

// ---------------- graph preprocessing ----------------

__global__ void k_hist(const int* __restrict__ row, const int* __restrict__ col,
                       unsigned* __restrict__ degcnt, unsigned* __restrict__ rowcnt) {
    for (int e = blockIdx.x * blockDim.x + threadIdx.x; e < NE; e += gridDim.x * blockDim.x) {
        atomicAdd(&rowcnt[row[e]], 1u);
        atomicAdd(&degcnt[col[e]], 1u);
    }
}

__global__ void k_dinv(const unsigned* __restrict__ degcnt, float* __restrict__ dinv) {
    int i = blockIdx.x * blockDim.x + threadIdx.x;
    if (i < NN) dinv[i] = rsqrtf((float)(degcnt[i] + 1u));  // +1 self loop
}

__global__ void k_scan_block(const unsigned* __restrict__ cnt, unsigned* __restrict__ excl,
                             unsigned* __restrict__ partials) {
    __shared__ unsigned s[256];
    int t = threadIdx.x;
    int i = blockIdx.x * 256 + t;
    unsigned v = (i < NN) ? cnt[i] : 0u;
    s[t] = v;
    __syncthreads();
    for (int off = 1; off < 256; off <<= 1) {
        unsigned x = (t >= off) ? s[t - off] : 0u;
        __syncthreads();
        s[t] += x;
        __syncthreads();
    }
    if (i < NN) excl[i] = s[t] - v;
    if (t == 255) partials[blockIdx.x] = s[255];
}

__global__ void k_scan_partials(unsigned* __restrict__ partials, int n) {
    __shared__ unsigned s[256];
    int t = threadIdx.x;
    unsigned v = (t < n) ? partials[t] : 0u;
    s[t] = v;
    __syncthreads();
    for (int off = 1; off < 256; off <<= 1) {
        unsigned x = (t >= off) ? s[t - off] : 0u;
        __syncthreads();
        s[t] += x;
        __syncthreads();
    }
    if (t < n) partials[t] = s[t] - v;
}

__global__ void k_scan_add(unsigned* __restrict__ rowptr, const unsigned* __restrict__ partials,
                           unsigned* __restrict__ cursor) {
    int i = blockIdx.x * blockDim.x + threadIdx.x;
    if (i < NN) {
        unsigned p = rowptr[i] + partials[i >> 8];
        rowptr[i] = p;
        cursor[i] = p;
    }
    if (i == 0) rowptr[NN] = NE;
}

__global__ void k_fill(const int* __restrict__ row, const int* __restrict__ col,
                       unsigned* __restrict__ cursor, int* __restrict__ colidx) {
    for (int e = blockIdx.x * blockDim.x + threadIdx.x; e < NE; e += gridDim.x * blockDim.x) {
        int r = row[e];
        unsigned p = atomicAdd(&cursor[r], 1u);
        colidx[p] = col[e];
    }
}

// ---------------- weight prep: bf16 + transpose ----------------
// Wt1[n*128+k] = bf16(W1[k*256+n]); Wt2[n*256+k] = bf16(W2[k*256+n])
__global__ void k_prep_w(const float* __restrict__ W1, const float* __restrict__ W2,
                         ushort* __restrict__ Wt1, ushort* __restrict__ Wt2) {
    int i = blockIdx.x * 256 + threadIdx.x;
    if (i < 128 * 256) { int k = i / 256, n = i % 256; Wt1[n * 128 + k] = f2bf(W1[i]); }
    if (i < 256 * 256) { int k = i / 256, n = i % 256; Wt2[n * 256 + k] = f2bf(W2[i]); }
}

__global__ void k_cast_x(const float* __restrict__ x, ushort* __restrict__ xb) {
    int i = blockIdx.x * 256 + threadIdx.x;  // over N*128/4
    if (i >= NN * IN_DIM / 4) return;
    float4 v = ((const float4*)x)[i];
    ushort4 o; o.x = f2bf(v.x); o.y = f2bf(v.y); o.z = f2bf(v.z); o.w = f2bf(v.w);
    ((ushort4*)xb)[i] = o;
}

// ---------------- MFMA GEMM: Y[N x 256](bf16) = A[N x K](bf16) @ Bt^T ----------------
// Bt is [256][K] bf16 (pre-transposed W). Block: 64 rows x 128 cols, 4 waves.
template <int K>
__global__ __launch_bounds__(256) void k_gemm_mfma(const ushort* __restrict__ A,
                                                   const ushort* __restrict__ Bt,
                                                   ushort* __restrict__ Y) {
    constexpr int BK = 32;
    constexpr int LD = 40;  // padded LDS stride (2-way bank conflicts only)
    __shared__ ushort sA[64 * LD];
    __shared__ ushort sB[128 * LD];
    int t = threadIdx.x;
    int wave = t >> 6, lane = t & 63;
    int quad = lane >> 4, m15 = lane & 15;
    long r0 = (long)blockIdx.x * 64;
    int n0 = blockIdx.y * 128;

    f32x4 acc[8];
#pragma unroll
    for (int i = 0; i < 8; i++) { acc[i][0] = 0.f; acc[i][1] = 0.f; acc[i][2] = 0.f; acc[i][3] = 0.f; }

    for (int k0 = 0; k0 < K; k0 += BK) {
        // stage A: 64 rows x 32 k; thread t -> row t/4, k-seg (t%4)*8 (16B)
        {
            int row = t >> 2, seg = (t & 3) * 8;
            long gr = r0 + row;
            uint4 v = make_uint4(0, 0, 0, 0);
            if (gr < NN) v = *(const uint4*)(A + gr * K + k0 + seg);
            *(uint4*)(sA + row * LD + seg) = v;
        }
        // stage B: 128 n x 32 k; thread t -> n = t/2, k-seg (t%2)*16 (32B)
        {
            int n = t >> 1, seg = (t & 1) * 16;
            const uint4* src = (const uint4*)(Bt + (long)(n0 + n) * K + k0 + seg);
            uint4 b0 = src[0], b1 = src[1];
            *(uint4*)(sB + n * LD + seg) = b0;
            *(uint4*)(sB + n * LD + seg + 8) = b1;
        }
        __syncthreads();
        short8 a = *(const short8*)(sA + (wave * 16 + m15) * LD + quad * 8);
#pragma unroll
        for (int ct = 0; ct < 8; ct++) {
            short8 b = *(const short8*)(sB + (ct * 16 + m15) * LD + quad * 8);
            acc[ct] = __builtin_amdgcn_mfma_f32_16x16x32_bf16(a, b, acc[ct], 0, 0, 0);
        }
        __syncthreads();
    }
    // store: C row = quad*4 + reg, col = lane&15 (per 16x16 tile)
    long rowbase = r0 + wave * 16 + quad * 4;
#pragma unroll
    for (int ct = 0; ct < 8; ct++) {
        int col = n0 + ct * 16 + m15;
#pragma unroll
        for (int rg = 0; rg < 4; rg++) {
            long gr = rowbase + rg;
            if (gr < NN) Y[gr * 256 + col] = f2bf(acc[ct][rg]);
        }
    }
}

// Y3[N x 40] = Hb[N x 256](bf16) @ W3[256 x 40](fp32); 320 thr = 8 rows x 40 cols
__global__ __launch_bounds__(320) void k_gemm_out(const ushort* __restrict__ A,
                                                  const float* __restrict__ W,
                                                  float* __restrict__ Y) {
    __shared__ float sh[8 * 256];
    int t = threadIdx.x;
    long r0 = (long)blockIdx.x * 8;
    for (int idx = t; idx < 2048; idx += 320) sh[idx] = bflo((unsigned)A[r0 * 256 + idx]);
    __syncthreads();
    int lr = t / 40, lc = t % 40;
    float acc = 0.f;
#pragma unroll 4
    for (int k = 0; k < 256; k++) acc += sh[lr * 256 + k] * W[k * 40 + lc];
    Y[(r0 + lr) * 40 + lc] = acc;
}

// ---------------- aggregation ----------------
// H[r] = dinv[r] * ( sum_{c in N(r)} dinv[c]*Y[c] + dinv[r]*Y[r] ) + bias   (Y in bf16)
__global__ __launch_bounds__(64) void k_agg_hid(const ushort* __restrict__ Y,
                                                const unsigned* __restrict__ rowptr,
                                                const int* __restrict__ colidx,
                                                const float* __restrict__ dinv,
                                                const float* __restrict__ bias,
                                                float* __restrict__ H) {
    int r = blockIdx.x;
    int t = threadIdx.x;  // 64 threads x 4 cols (uint2 = 4 bf16)
    const uint2* Yv = (const uint2*)Y;  // 64 uint2 per 256-col row
    float dr = dinv[r];
    uint2 y = Yv[(size_t)r * 64 + t];
    float a0 = dr * bflo(y.x), a1 = dr * bfhi(y.x), a2 = dr * bflo(y.y), a3 = dr * bfhi(y.y);
    unsigned e0 = rowptr[r], e1 = rowptr[r + 1];
    for (unsigned e = e0; e < e1; e++) {
        int c = colidx[e];
        float dc = dinv[c];
        uint2 v = Yv[(size_t)c * 64 + t];
        a0 += dc * bflo(v.x); a1 += dc * bfhi(v.x);
        a2 += dc * bflo(v.y); a3 += dc * bfhi(v.y);
    }
    const float4 b = ((const float4*)bias)[t];
    float4 o;
    o.x = dr * a0 + b.x; o.y = dr * a1 + b.y; o.z = dr * a2 + b.z; o.w = dr * a3 + b.w;
    ((float4*)H)[(size_t)r * 64 + t] = o;
}

__global__ __launch_bounds__(64) void k_agg_out(const float* __restrict__ Y,
                                                const unsigned* __restrict__ rowptr,
                                                const int* __restrict__ colidx,
                                                const float* __restrict__ dinv,
                                                const float* __restrict__ bias,
                                                float* __restrict__ H) {
    int r = blockIdx.x;
    int t = threadIdx.x;
    if (t >= OUT_DIM) return;
    float dr = dinv[r];
    float acc = dr * Y[(size_t)r * OUT_DIM + t];
    unsigned e0 = rowptr[r], e1 = rowptr[r + 1];
    for (unsigned e = e0; e < e1; e++) {
        int c = colidx[e];
        acc += dinv[c] * Y[(size_t)c * OUT_DIM + t];
    }
    H[(size_t)r * OUT_DIM + t] = dr * acc + bias[t];
}

// ---------------- BatchNorm ----------------
__global__ __launch_bounds__(256) void k_bn_stats(const float* __restrict__ H, float* __restrict__ bn) {
    int t = threadIdx.x;
    int b = blockIdx.x;
    int rows_per = (NN + gridDim.x - 1) / gridDim.x;
    int r0 = b * rows_per;
    int r1 = r0 + rows_per; if (r1 > NN) r1 = NN;
    float s = 0.f, sq = 0.f;
    for (int r = r0; r < r1; r++) {
        float v = H[(size_t)r * 256 + t];
        s += v; sq += v * v;
    }
    atomicAdd(&bn[t], s);
    atomicAdd(&bn[256 + t], sq);
}

__global__ void k_bn_final(float* __restrict__ bn, const float* __restrict__ gamma,
                           const float* __restrict__ beta) {
    int t = threadIdx.x;
    float mu = bn[t] * (1.f / NN);
    float var = bn[256 + t] * (1.f / NN) - mu * mu;
    float rstd = rsqrtf(var + BN_EPS);
    float g = gamma[t] * rstd;
    bn[512 + t] = g;
    bn[768 + t] = beta[t] - mu * g;
}

// read H fp32, write relu(bn(H)) as bf16 into Hb
__global__ __launch_bounds__(256) void k_bn_apply(const float* __restrict__ H,
                                                  const float* __restrict__ bn,
                                                  ushort* __restrict__ Hb) {
    size_t i = (size_t)blockIdx.x * blockDim.x + threadIdx.x;  // over N*256/4
    float4 v = ((const float4*)H)[i];
    int c4 = (int)(i & 63);
    float4 sc = ((const float4*)(bn + 512))[c4];
    float4 sf = ((const float4*)(bn + 768))[c4];
    ushort4 o;
    o.x = f2bf(fmaxf(v.x * sc.x + sf.x, 0.f));
    o.y = f2bf(fmaxf(v.y * sc.y + sf.y, 0.f));
    o.z = f2bf(fmaxf(v.z * sc.z + sf.z, 0.f));
    o.w = f2bf(fmaxf(v.w * sc.w + sf.w, 0.f));
    ((ushort4*)Hb)[i] = o;
}

// ---------------- log_softmax ----------------
__global__ __launch_bounds__(256) void k_lsm(const float* __restrict__ H, float* __restrict__ out) {
    int r = blockIdx.x * blockDim.x + threadIdx.x;
    if (r >= NN) return;
    const float* p = H + (size_t)r * OUT_DIM;
    float m = -1e30f;
#pragma unroll
    for (int j = 0; j < OUT_DIM; j++) m = fmaxf(m, p[j]);
    float s = 0.f;
#pragma unroll
    for (int j = 0; j < OUT_DIM; j++) s += expf(p[j] - m);
    float ls = logf(s) + m;
    float* o = out + (size_t)r * OUT_DIM;
#pragma unroll
    for (int j = 0; j < OUT_DIM; j++) o[j] = p[j] - ls;
}

// ---------------- launch ----------------

extern "C" void kernel_launch(void* const* d_in, const int* in_sizes, int n_in,
                              void* d_out, int out_size, void* d_ws, size_t ws_size,
                              hipStream_t stream) {
    const float* x     = (const float*)d_in[0];
    const int*   erow  = (const int*)d_in[1];
    const int*   ecol  = ((const int*)d_in[1]) + NE;
    const float* W1    = (const float*)d_in[2];
    const float* b1    = (const float*)d_in[3];
    const float* W2    = (const float*)d_in[4];
    const float* b2    = (const float*)d_in[5];
    const float* W3    = (const float*)d_in[6];
    const float* b3    = (const float*)d_in[7];
    const float* gamma = (const float*)d_in[8];
    const float* beta  = (const float*)d_in[9];
    float* out = (float*)d_out;

    char* ws = (char*)d_ws;
    size_t off = 0;
    auto alloc = [&](size_t bytes) -> void* {
        void* p = ws + off;
        off = (off + bytes + 255) & ~(size_t)255;
        return p;
    };
    unsigned* degcnt   = (unsigned*)alloc(NN * 4);
    float*    dinv     = (float*)alloc(NN * 4);
    unsigned* rowcnt   = (unsigned*)alloc(NN * 4);
    unsigned* rowptr   = (unsigned*)alloc((NN + 1) * 4);
    unsigned* cursor   = (unsigned*)alloc(NN * 4);
    unsigned* partials = (unsigned*)alloc(256 * 4);
    int*      colidx   = (int*)alloc((size_t)NE * 4);
    float*    bn       = (float*)alloc(1024 * 4);
    ushort*   Wt1      = (ushort*)alloc(128 * 256 * 2);
    ushort*   Wt2      = (ushort*)alloc(256 * 256 * 2);
    // xb (N x 128 bf16, 12.8MB) aliases Hb (N x 256 bf16, 25.6MB): xb dead after gemm1
    ushort*   Hb       = (ushort*)alloc((size_t)NN * HID * 2);
    ushort*   xb       = Hb;
    // Yb (bf16) aliases Y3 (fp32 N x 40): Yb dead before gemm_out writes Y3
    ushort*   Yb       = (ushort*)alloc((size_t)NN * HID * 2);
    float*    Y3       = (float*)Yb;
    float*    H        = (float*)alloc((size_t)NN * HID * 4);

    const int nscan = (NN + 255) / 256;  // 196

    // --- graph preprocessing + input prep ---
    hipMemsetAsync(degcnt, 0, NN * 4, stream);
    hipMemsetAsync(rowcnt, 0, NN * 4, stream);
    k_hist<<<1024, 256, 0, stream>>>(erow, ecol, degcnt, rowcnt);
    k_dinv<<<nscan, 256, 0, stream>>>(degcnt, dinv);
    k_scan_block<<<nscan, 256, 0, stream>>>(rowcnt, rowptr, partials);
    k_scan_partials<<<1, 256, 0, stream>>>(partials, nscan);
    k_scan_add<<<nscan, 256, 0, stream>>>(rowptr, partials, cursor);
    k_fill<<<1024, 256, 0, stream>>>(erow, ecol, cursor, colidx);
    k_prep_w<<<256, 256, 0, stream>>>(W1, W2, Wt1, Wt2);
    k_cast_x<<<(NN * IN_DIM / 4 + 255) / 256, 256, 0, stream>>>(x, xb);

    dim3 ggrid((NN + 63) / 64, 2);

    // --- layer 1 ---
    k_gemm_mfma<IN_DIM><<<ggrid, 256, 0, stream>>>(xb, Wt1, Yb);
    k_agg_hid<<<NN, 64, 0, stream>>>(Yb, rowptr, colidx, dinv, b1, H);
    hipMemsetAsync(bn, 0, 512 * 4, stream);
    k_bn_stats<<<256, 256, 0, stream>>>(H, bn);
    k_bn_final<<<1, 256, 0, stream>>>(bn, gamma, beta);
    k_bn_apply<<<(NN * HID / 4) / 256, 256, 0, stream>>>(H, bn, Hb);

    // --- layer 2 ---
    k_gemm_mfma<HID><<<ggrid, 256, 0, stream>>>(Hb, Wt2, Yb);
    k_agg_hid<<<NN, 64, 0, stream>>>(Yb, rowptr, colidx, dinv, b2, H);
    hipMemsetAsync(bn, 0, 512 * 4, stream);
    k_bn_stats<<<256, 256, 0, stream>>>(H, bn);
    k_bn_final<<<1, 256, 0, stream>>>(bn, gamma, beta);
    k_bn_apply<<<(NN * HID / 4) / 256, 256, 0, stream>>>(H, bn, Hb);

    // --- layer 3 ---
    k_gemm_out<<<NN / 8, 320, 0, stream>>>(Hb, W3, Y3);
    k_agg_out<<<NN, 64, 0, stream>>>(Y3, rowptr, colidx, dinv, b3, H);
    k_lsm<<<(NN + 255) / 256, 256, 0, stream>>>(H, out);
}

// Round 3
// 568.562 us; speedup vs baseline: 1.6150x; 1.1892x over previous
//
#include <hip/hip_runtime.h>
#include <math.h>

#define NN 50000
#define NE 800000
#define IN_DIM 128
#define HID 256
#define OUT_DIM 40
#define BN_EPS 1e-5f

typedef __attribute__((ext_vector_type(8))) short short8;
typedef __attribute__((ext_vector_type(4))) float f32x4;

__device__ __forceinline__ ushort f2bf(float f) {
    union { float f; unsigned u; } v; v.f = f;
    unsigned r = v.u + 0x7fffu + ((v.u >> 16) & 1u);
    return (ushort)(r >> 16);
}
__device__ __forceinline__ float bflo(unsigned u) {
    union { unsigned a; float f; } v; v.a = u << 16; return v.f;
}
__device__ __forceinline__ float bfhi(unsigned u) {
    union { unsigned a; float f; } v; v.a = u & 0xffff0000u; return v.f;
}

// ---------------- graph preprocessing ----------------

__global__ void k_hist(const int* __restrict__ row, const int* __restrict__ col,
                       unsigned* __restrict__ degcnt, unsigned* __restrict__ rowcnt) {
    for (int e = blockIdx.x * blockDim.x + threadIdx.x; e < NE; e += gridDim.x * blockDim.x) {
        atomicAdd(&rowcnt[row[e]], 1u);
        atomicAdd(&degcnt[col[e]], 1u);
    }
}

__global__ void k_dinv(const unsigned* __restrict__ degcnt, float* __restrict__ dinv) {
    int i = blockIdx.x * blockDim.x + threadIdx.x;
    if (i < NN) dinv[i] = rsqrtf((float)(degcnt[i] + 1u));  // +1 self loop
}

__global__ void k_scan_block(const unsigned* __restrict__ cnt, unsigned* __restrict__ excl,
                             unsigned* __restrict__ partials) {
    __shared__ unsigned s[256];
    int t = threadIdx.x;
    int i = blockIdx.x * 256 + t;
    unsigned v = (i < NN) ? cnt[i] : 0u;
    s[t] = v;
    __syncthreads();
    for (int off = 1; off < 256; off <<= 1) {
        unsigned x = (t >= off) ? s[t - off] : 0u;
        __syncthreads();
        s[t] += x;
        __syncthreads();
    }
    if (i < NN) excl[i] = s[t] - v;
    if (t == 255) partials[blockIdx.x] = s[255];
}

__global__ void k_scan_partials(unsigned* __restrict__ partials, int n) {
    __shared__ unsigned s[256];
    int t = threadIdx.x;
    unsigned v = (t < n) ? partials[t] : 0u;
    s[t] = v;
    __syncthreads();
    for (int off = 1; off < 256; off <<= 1) {
        unsigned x = (t >= off) ? s[t - off] : 0u;
        __syncthreads();
        s[t] += x;
        __syncthreads();
    }
    if (t < n) partials[t] = s[t] - v;
}

__global__ void k_scan_add(unsigned* __restrict__ rowptr, const unsigned* __restrict__ partials,
                           unsigned* __restrict__ cursor) {
    int i = blockIdx.x * blockDim.x + threadIdx.x;
    if (i < NN) {
        unsigned p = rowptr[i] + partials[i >> 8];
        rowptr[i] = p;
        cursor[i] = p;
    }
    if (i == 0) rowptr[NN] = NE;
}

__global__ void k_fill(const int* __restrict__ row, const int* __restrict__ col,
                       unsigned* __restrict__ cursor, int* __restrict__ colidx) {
    for (int e = blockIdx.x * blockDim.x + threadIdx.x; e < NE; e += gridDim.x * blockDim.x) {
        int r = row[e];
        unsigned p = atomicAdd(&cursor[r], 1u);
        colidx[p] = col[e];
    }
}

// ---------------- weight prep: bf16 + transpose ----------------
__global__ void k_prep_w(const float* __restrict__ W1, const float* __restrict__ W2,
                         const float* __restrict__ W3,
                         ushort* __restrict__ Wt1, ushort* __restrict__ Wt2,
                         ushort* __restrict__ Wt3) {
    int i = blockIdx.x * 256 + threadIdx.x;
    if (i < 128 * 256) { int k = i / 256, n = i % 256; Wt1[n * 128 + k] = f2bf(W1[i]); }
    if (i < 256 * 256) { int k = i / 256, n = i % 256; Wt2[n * 256 + k] = f2bf(W2[i]); }
    if (i < 48 * 256)  { int n = i / 256, k = i % 256;
                         Wt3[i] = (n < OUT_DIM) ? f2bf(W3[k * OUT_DIM + n]) : (ushort)0; }
}

// xs = bf16(dinv[row] * x)  (pre-scaled source features)
__global__ void k_cast_x(const float* __restrict__ x, const float* __restrict__ dinv,
                         ushort* __restrict__ xs) {
    int i = blockIdx.x * 256 + threadIdx.x;  // over N*128/4 float4 groups
    if (i >= NN * IN_DIM / 4) return;
    int row = i >> 5;  // 32 float4 per row
    float d = dinv[row];
    float4 v = ((const float4*)x)[i];
    ushort4 o;
    o.x = f2bf(v.x * d); o.y = f2bf(v.y * d); o.z = f2bf(v.z * d); o.w = f2bf(v.w * d);
    ((ushort4*)xs)[i] = o;
}

// ---------------- layer-1 aggregation on raw features (128-dim) ----------------
// Xa[r] = bf16( dinv[r] * ( sum_{c in N(r)} xs[c] + xs[r] ) )
__global__ __launch_bounds__(64) void k_agg_x(const ushort* __restrict__ xs,
                                              const unsigned* __restrict__ rowptr,
                                              const int* __restrict__ colidx,
                                              const float* __restrict__ dinv,
                                              ushort* __restrict__ Xa) {
    int r = blockIdx.x;
    int t = threadIdx.x;  // 64 threads x 2 cols (uint = 2 bf16) = 128 cols
    const unsigned* Xv = (const unsigned*)xs;
    unsigned y = Xv[(size_t)r * 64 + t];
    float a0 = bflo(y), a1 = bfhi(y);
    unsigned e0 = rowptr[r], e1 = rowptr[r + 1];
    for (unsigned e = e0; e < e1; e++) {
        int c = colidx[e];
        unsigned v = Xv[(size_t)c * 64 + t];
        a0 += bflo(v); a1 += bfhi(v);
    }
    float dr = dinv[r];
    ((unsigned*)Xa)[(size_t)r * 64 + t] = (unsigned)f2bf(dr * a0) | ((unsigned)f2bf(dr * a1) << 16);
}

// ---------------- MFMA GEMM 1: H[N x 256](fp32) = Xa[N x 128](bf16) @ Wt1^T ----------------
template <int K>
__global__ __launch_bounds__(256) void k_gemm1(const ushort* __restrict__ A,
                                               const ushort* __restrict__ Bt,
                                               float* __restrict__ H) {
    constexpr int BK = 32;
    constexpr int LD = 40;
    __shared__ ushort sA[64 * LD];
    __shared__ ushort sB[128 * LD];
    int t = threadIdx.x;
    int wave = t >> 6, lane = t & 63;
    int quad = lane >> 4, m15 = lane & 15;
    long r0 = (long)blockIdx.x * 64;
    int n0 = blockIdx.y * 128;

    f32x4 acc[8];
#pragma unroll
    for (int i = 0; i < 8; i++) { acc[i][0] = 0.f; acc[i][1] = 0.f; acc[i][2] = 0.f; acc[i][3] = 0.f; }

    for (int k0 = 0; k0 < K; k0 += BK) {
        {
            int row = t >> 2, seg = (t & 3) * 8;
            long gr = r0 + row;
            uint4 v = make_uint4(0, 0, 0, 0);
            if (gr < NN) v = *(const uint4*)(A + gr * K + k0 + seg);
            *(uint4*)(sA + row * LD + seg) = v;
        }
        {
            int n = t >> 1, seg = (t & 1) * 16;
            const uint4* src = (const uint4*)(Bt + (long)(n0 + n) * K + k0 + seg);
            uint4 b0 = src[0], b1 = src[1];
            *(uint4*)(sB + n * LD + seg) = b0;
            *(uint4*)(sB + n * LD + seg + 8) = b1;
        }
        __syncthreads();
        short8 a = *(const short8*)(sA + (wave * 16 + m15) * LD + quad * 8);
#pragma unroll
        for (int ct = 0; ct < 8; ct++) {
            short8 b = *(const short8*)(sB + (ct * 16 + m15) * LD + quad * 8);
            acc[ct] = __builtin_amdgcn_mfma_f32_16x16x32_bf16(a, b, acc[ct], 0, 0, 0);
        }
        __syncthreads();
    }
    long rowbase = r0 + wave * 16 + quad * 4;
#pragma unroll
    for (int ct = 0; ct < 8; ct++) {
        int col = n0 + ct * 16 + m15;
#pragma unroll
        for (int rg = 0; rg < 4; rg++) {
            long gr = rowbase + rg;
            if (gr < NN) H[gr * 256 + col] = acc[ct][rg];
        }
    }
}

// ---------------- MFMA GEMM 2: Ys2 = bf16( dinv * (relu(bn(H)) @ Wt2^T) ) ----------------
__global__ __launch_bounds__(256) void k_gemm2(const float* __restrict__ H,
                                               const float* __restrict__ bn,
                                               const ushort* __restrict__ Bt,
                                               const float* __restrict__ dinv,
                                               ushort* __restrict__ Y) {
    constexpr int K = 256, BK = 32, LD = 40;
    __shared__ ushort sA[64 * LD];
    __shared__ ushort sB[128 * LD];
    int t = threadIdx.x;
    int wave = t >> 6, lane = t & 63;
    int quad = lane >> 4, m15 = lane & 15;
    long r0 = (long)blockIdx.x * 64;
    int n0 = blockIdx.y * 128;

    f32x4 acc[8];
#pragma unroll
    for (int i = 0; i < 8; i++) { acc[i][0] = 0.f; acc[i][1] = 0.f; acc[i][2] = 0.f; acc[i][3] = 0.f; }

    for (int k0 = 0; k0 < K; k0 += BK) {
        {
            int row = t >> 2, seg = (t & 3) * 8;
            long gr = r0 + row;
            float4 h0 = make_float4(0, 0, 0, 0), h1 = h0;
            if (gr < NN) {
                h0 = *(const float4*)(H + gr * 256 + k0 + seg);
                h1 = *(const float4*)(H + gr * 256 + k0 + seg + 4);
            }
            float4 sc0 = *(const float4*)(bn + 512 + k0 + seg);
            float4 sc1 = *(const float4*)(bn + 512 + k0 + seg + 4);
            float4 sf0 = *(const float4*)(bn + 768 + k0 + seg);
            float4 sf1 = *(const float4*)(bn + 768 + k0 + seg + 4);
            ushort* dst = sA + row * LD + seg;
            dst[0] = f2bf(fmaxf(h0.x * sc0.x + sf0.x, 0.f));
            dst[1] = f2bf(fmaxf(h0.y * sc0.y + sf0.y, 0.f));
            dst[2] = f2bf(fmaxf(h0.z * sc0.z + sf0.z, 0.f));
            dst[3] = f2bf(fmaxf(h0.w * sc0.w + sf0.w, 0.f));
            dst[4] = f2bf(fmaxf(h1.x * sc1.x + sf1.x, 0.f));
            dst[5] = f2bf(fmaxf(h1.y * sc1.y + sf1.y, 0.f));
            dst[6] = f2bf(fmaxf(h1.z * sc1.z + sf1.z, 0.f));
            dst[7] = f2bf(fmaxf(h1.w * sc1.w + sf1.w, 0.f));
        }
        {
            int n = t >> 1, seg = (t & 1) * 16;
            const uint4* src = (const uint4*)(Bt + (long)(n0 + n) * K + k0 + seg);
            uint4 b0 = src[0], b1 = src[1];
            *(uint4*)(sB + n * LD + seg) = b0;
            *(uint4*)(sB + n * LD + seg + 8) = b1;
        }
        __syncthreads();
        short8 a = *(const short8*)(sA + (wave * 16 + m15) * LD + quad * 8);
#pragma unroll
        for (int ct = 0; ct < 8; ct++) {
            short8 b = *(const short8*)(sB + (ct * 16 + m15) * LD + quad * 8);
            acc[ct] = __builtin_amdgcn_mfma_f32_16x16x32_bf16(a, b, acc[ct], 0, 0, 0);
        }
        __syncthreads();
    }
    long rowbase = r0 + wave * 16 + quad * 4;
#pragma unroll
    for (int ct = 0; ct < 8; ct++) {
        int col = n0 + ct * 16 + m15;
#pragma unroll
        for (int rg = 0; rg < 4; rg++) {
            long gr = rowbase + rg;
            if (gr < NN) Y[gr * 256 + col] = f2bf(dinv[gr] * acc[ct][rg]);
        }
    }
}

// ---------------- MFMA GEMM 3: Ys3[N x 64-stride](bf16) = dinv * (relu(bn(H)) @ Wt3^T) ----------------
// 64 rows x 48 cols per block; whole Wt3 in LDS.
__global__ __launch_bounds__(256) void k_gemm3(const float* __restrict__ H,
                                               const float* __restrict__ bn,
                                               const ushort* __restrict__ Wt3,
                                               const float* __restrict__ dinv,
                                               ushort* __restrict__ Y) {
    constexpr int LD = 264;
    __shared__ ushort sA[64 * LD];
    __shared__ ushort sB[48 * LD];
    int t = threadIdx.x;
    int wave = t >> 6, lane = t & 63;
    int quad = lane >> 4, m15 = lane & 15;
    long r0 = (long)blockIdx.x * 64;

    // stage B: whole 48 x 256
    for (int idx = t; idx < 48 * 16; idx += 256) {
        int n = idx >> 4, s = (idx & 15) * 16;
        const uint4* src = (const uint4*)(Wt3 + n * 256 + s);
        *(uint4*)(sB + n * LD + s) = src[0];
        *(uint4*)(sB + n * LD + s + 8) = src[1];
    }
    // stage A: 64 rows x 256 cols with fused BN+ReLU
    {
        int row = t >> 2;
        long gr = r0 + row;
        for (int s8 = 0; s8 < 8; s8++) {
            int seg = s8 * 32 + (t & 3) * 8;
            float4 h0 = make_float4(0, 0, 0, 0), h1 = h0;
            if (gr < NN) {
                h0 = *(const float4*)(H + gr * 256 + seg);
                h1 = *(const float4*)(H + gr * 256 + seg + 4);
            }
            float4 sc0 = *(const float4*)(bn + 512 + seg);
            float4 sc1 = *(const float4*)(bn + 512 + seg + 4);
            float4 sf0 = *(const float4*)(bn + 768 + seg);
            float4 sf1 = *(const float4*)(bn + 768 + seg + 4);
            ushort* dst = sA + row * LD + seg;
            dst[0] = f2bf(fmaxf(h0.x * sc0.x + sf0.x, 0.f));
            dst[1] = f2bf(fmaxf(h0.y * sc0.y + sf0.y, 0.f));
            dst[2] = f2bf(fmaxf(h0.z * sc0.z + sf0.z, 0.f));
            dst[3] = f2bf(fmaxf(h0.w * sc0.w + sf0.w, 0.f));
            dst[4] = f2bf(fmaxf(h1.x * sc1.x + sf1.x, 0.f));
            dst[5] = f2bf(fmaxf(h1.y * sc1.y + sf1.y, 0.f));
            dst[6] = f2bf(fmaxf(h1.z * sc1.z + sf1.z, 0.f));
            dst[7] = f2bf(fmaxf(h1.w * sc1.w + sf1.w, 0.f));
        }
    }
    __syncthreads();

    f32x4 acc[3];
#pragma unroll
    for (int i = 0; i < 3; i++) { acc[i][0] = 0.f; acc[i][1] = 0.f; acc[i][2] = 0.f; acc[i][3] = 0.f; }
#pragma unroll
    for (int k0 = 0; k0 < 256; k0 += 32) {
        short8 a = *(const short8*)(sA + (wave * 16 + m15) * LD + k0 + quad * 8);
#pragma unroll
        for (int ct = 0; ct < 3; ct++) {
            short8 b = *(const short8*)(sB + (ct * 16 + m15) * LD + k0 + quad * 8);
            acc[ct] = __builtin_amdgcn_mfma_f32_16x16x32_bf16(a, b, acc[ct], 0, 0, 0);
        }
    }
    long rowbase = r0 + wave * 16 + quad * 4;
#pragma unroll
    for (int ct = 0; ct < 3; ct++) {
        int col = ct * 16 + m15;
#pragma unroll
        for (int rg = 0; rg < 4; rg++) {
            long gr = rowbase + rg;
            if (gr < NN) Y[gr * 64 + col] = f2bf(dinv[gr] * acc[ct][rg]);
        }
    }
}

// ---------------- layer-2 aggregation (256-dim bf16, pre-scaled) ----------------
// H[r] = dinv[r] * ( sum_{c in N(r)} Ys[c] + Ys[r] )   (fp32 out, no bias)
__global__ __launch_bounds__(64) void k_agg_hid(const ushort* __restrict__ Y,
                                                const unsigned* __restrict__ rowptr,
                                                const int* __restrict__ colidx,
                                                const float* __restrict__ dinv,
                                                float* __restrict__ H) {
    int r = blockIdx.x;
    int t = threadIdx.x;
    const uint2* Yv = (const uint2*)Y;
    uint2 y = Yv[(size_t)r * 64 + t];
    float a0 = bflo(y.x), a1 = bfhi(y.x), a2 = bflo(y.y), a3 = bfhi(y.y);
    unsigned e0 = rowptr[r], e1 = rowptr[r + 1];
    for (unsigned e = e0; e < e1; e++) {
        int c = colidx[e];
        uint2 v = Yv[(size_t)c * 64 + t];
        a0 += bflo(v.x); a1 += bfhi(v.x);
        a2 += bflo(v.y); a3 += bfhi(v.y);
    }
    float dr = dinv[r];
    float4 o;
    o.x = dr * a0; o.y = dr * a1; o.z = dr * a2; o.w = dr * a3;
    ((float4*)H)[(size_t)r * 64 + t] = o;
}

// ---------------- layer-3 aggregation + bias + log_softmax fused ----------------
__global__ __launch_bounds__(64) void k_agg_lsm(const ushort* __restrict__ Y,
                                                const unsigned* __restrict__ rowptr,
                                                const int* __restrict__ colidx,
                                                const float* __restrict__ dinv,
                                                const float* __restrict__ b3,
                                                float* __restrict__ out) {
    int r = blockIdx.x;
    int t = threadIdx.x;
    float acc = 0.f;
    if (t < OUT_DIM) acc = bflo((unsigned)Y[(size_t)r * 64 + t]);
    unsigned e0 = rowptr[r], e1 = rowptr[r + 1];
    for (unsigned e = e0; e < e1; e++) {
        int c = colidx[e];
        if (t < OUT_DIM) acc += bflo((unsigned)Y[(size_t)c * 64 + t]);
    }
    float o = 0.f;
    if (t < OUT_DIM) o = dinv[r] * acc + b3[t];
    // 64-lane butterfly max / sum
    float m = (t < OUT_DIM) ? o : -1e30f;
#pragma unroll
    for (int d = 1; d < 64; d <<= 1) m = fmaxf(m, __shfl_xor(m, d, 64));
    float e = (t < OUT_DIM) ? expf(o - m) : 0.f;
#pragma unroll
    for (int d = 1; d < 64; d <<= 1) e += __shfl_xor(e, d, 64);
    float ls = logf(e) + m;
    if (t < OUT_DIM) out[(size_t)r * OUT_DIM + t] = o - ls;
}

// ---------------- BatchNorm ----------------
__global__ __launch_bounds__(256) void k_bn_stats(const float* __restrict__ H, float* __restrict__ bn) {
    int t = threadIdx.x;
    int b = blockIdx.x;
    int rows_per = (NN + gridDim.x - 1) / gridDim.x;
    int r0 = b * rows_per;
    int r1 = r0 + rows_per; if (r1 > NN) r1 = NN;
    float s = 0.f, sq = 0.f;
    for (int r = r0; r < r1; r++) {
        float v = H[(size_t)r * 256 + t];
        s += v; sq += v * v;
    }
    atomicAdd(&bn[t], s);
    atomicAdd(&bn[256 + t], sq);
}

__global__ void k_bn_final(float* __restrict__ bn, const float* __restrict__ gamma,
                           const float* __restrict__ beta) {
    int t = threadIdx.x;
    float mu = bn[t] * (1.f / NN);
    float var = bn[256 + t] * (1.f / NN) - mu * mu;
    float rstd = rsqrtf(var + BN_EPS);
    float g = gamma[t] * rstd;
    bn[512 + t] = g;
    bn[768 + t] = beta[t] - mu * g;
}

// ---------------- launch ----------------

extern "C" void kernel_launch(void* const* d_in, const int* in_sizes, int n_in,
                              void* d_out, int out_size, void* d_ws, size_t ws_size,
                              hipStream_t stream) {
    const float* x     = (const float*)d_in[0];
    const int*   erow  = (const int*)d_in[1];
    const int*   ecol  = ((const int*)d_in[1]) + NE;
    const float* W1    = (const float*)d_in[2];
    const float* W2    = (const float*)d_in[4];
    const float* W3    = (const float*)d_in[6];
    const float* b3    = (const float*)d_in[7];
    const float* gamma = (const float*)d_in[8];
    const float* beta  = (const float*)d_in[9];
    float* out = (float*)d_out;

    char* ws = (char*)d_ws;
    size_t off = 0;
    auto alloc = [&](size_t bytes) -> void* {
        void* p = ws + off;
        off = (off + bytes + 255) & ~(size_t)255;
        return p;
    };
    unsigned* degcnt   = (unsigned*)alloc(NN * 4);
    float*    dinv     = (float*)alloc(NN * 4);
    unsigned* rowcnt   = (unsigned*)alloc(NN * 4);
    unsigned* rowptr   = (unsigned*)alloc((NN + 1) * 4);
    unsigned* cursor   = (unsigned*)alloc(NN * 4);
    unsigned* partials = (unsigned*)alloc(256 * 4);
    int*      colidx   = (int*)alloc((size_t)NE * 4);
    float*    bn       = (float*)alloc(1024 * 4);
    ushort*   Wt1      = (ushort*)alloc(128 * 256 * 2);
    ushort*   Wt2      = (ushort*)alloc(256 * 256 * 2);
    ushort*   Wt3      = (ushort*)alloc(48 * 256 * 2);
    ushort*   xs       = (ushort*)alloc((size_t)NN * IN_DIM * 2);   // dinv-scaled x, bf16
    ushort*   Xa       = (ushort*)alloc((size_t)NN * IN_DIM * 2);   // aggregated x
    float*    H        = (float*)alloc((size_t)NN * HID * 4);       // conv output fp32
    ushort*   Ys2      = (ushort*)alloc((size_t)NN * HID * 2);      // dinv-scaled layer2 transform
    ushort*   Ys3      = (ushort*)alloc((size_t)NN * 64 * 2);       // dinv-scaled layer3 transform (stride 64)

    const int nscan = (NN + 255) / 256;

    // --- graph preprocessing + input prep ---
    hipMemsetAsync(degcnt, 0, NN * 4, stream);
    hipMemsetAsync(rowcnt, 0, NN * 4, stream);
    k_hist<<<1024, 256, 0, stream>>>(erow, ecol, degcnt, rowcnt);
    k_dinv<<<nscan, 256, 0, stream>>>(degcnt, dinv);
    k_scan_block<<<nscan, 256, 0, stream>>>(rowcnt, rowptr, partials);
    k_scan_partials<<<1, 256, 0, stream>>>(partials, nscan);
    k_scan_add<<<nscan, 256, 0, stream>>>(rowptr, partials, cursor);
    k_fill<<<1024, 256, 0, stream>>>(erow, ecol, cursor, colidx);
    k_prep_w<<<256, 256, 0, stream>>>(W1, W2, W3, Wt1, Wt2, Wt3);
    k_cast_x<<<(NN * IN_DIM / 4 + 255) / 256, 256, 0, stream>>>(x, dinv, xs);

    dim3 ggrid((NN + 63) / 64, 2);

    // --- layer 1: aggregate-first (linear), then transform ---
    k_agg_x<<<NN, 64, 0, stream>>>(xs, rowptr, colidx, dinv, Xa);
    k_gemm1<IN_DIM><<<ggrid, 256, 0, stream>>>(Xa, Wt1, H);
    hipMemsetAsync(bn, 0, 512 * 4, stream);
    k_bn_stats<<<256, 256, 0, stream>>>(H, bn);
    k_bn_final<<<1, 256, 0, stream>>>(bn, gamma, beta);

    // --- layer 2: BN fused into GEMM staging; dinv fused into output ---
    k_gemm2<<<ggrid, 256, 0, stream>>>(H, bn, Wt2, dinv, Ys2);
    k_agg_hid<<<NN, 64, 0, stream>>>(Ys2, rowptr, colidx, dinv, H);
    hipMemsetAsync(bn, 0, 512 * 4, stream);
    k_bn_stats<<<256, 256, 0, stream>>>(H, bn);
    k_bn_final<<<1, 256, 0, stream>>>(bn, gamma, beta);

    // --- layer 3: BN fused into GEMM; agg + bias + log_softmax fused ---
    k_gemm3<<<(NN + 63) / 64, 256, 0, stream>>>(H, bn, Wt3, dinv, Ys3);
    k_agg_lsm<<<NN, 64, 0, stream>>>(Ys3, rowptr, colidx, dinv, b3, out);
}

// Round 4
// 486.933 us; speedup vs baseline: 1.8858x; 1.1676x over previous
//
#include <hip/hip_runtime.h>
#include <math.h>

#define NN 50000
#define NE 800000
#define IN_DIM 128
#define HID 256
#define OUT_DIM 40
#define BN_EPS 1e-5f

#define HG 128          // histogram blocks per array
#define HW 25000        // packed words (2 nodes/word)
#define HPASS 12800     // words per LDS pass

typedef __attribute__((ext_vector_type(8))) short short8;
typedef __attribute__((ext_vector_type(4))) float f32x4;

__device__ __forceinline__ ushort f2bf(float f) {
    union { float f; unsigned u; } v; v.f = f;
    unsigned r = v.u + 0x7fffu + ((v.u >> 16) & 1u);
    return (ushort)(r >> 16);
}
__device__ __forceinline__ float bflo(unsigned u) {
    union { unsigned a; float f; } v; v.a = u << 16; return v.f;
}
__device__ __forceinline__ float bfhi(unsigned u) {
    union { unsigned a; float f; } v; v.a = u & 0xffff0000u; return v.f;
}

// ---------------- histogram via LDS (no global atomics) ----------------
// grid (HG, 2): y=0 -> row array, y=1 -> col array. Packed 16-bit counters.
__global__ __launch_bounds__(512) void k_hist_lds(const int* __restrict__ erow,
                                                  const int* __restrict__ ecol,
                                                  unsigned* __restrict__ Prow,
                                                  unsigned* __restrict__ Pcol) {
    __shared__ unsigned lds[HPASS];
    int t = threadIdx.x;
    int b = blockIdx.x;
    const int* arr = (blockIdx.y == 0) ? erow : ecol;
    unsigned* partial = ((blockIdx.y == 0) ? Prow : Pcol) + (size_t)b * HW;
    int e0 = b * (NE / HG), e1 = e0 + (NE / HG);
#pragma unroll
    for (int pass = 0; pass < 2; pass++) {
        int wbase = pass ? HPASS : 0;
        int wend = pass ? HW : HPASS;
        int nw = wend - wbase;
        for (int w = t; w < HPASS; w += 512) lds[w] = 0u;
        __syncthreads();
        int vlo = wbase * 2, vhi = wend * 2;
        for (int e = e0 + t; e < e1; e += 512) {
            int v = arr[e];
            if (v >= vlo && v < vhi)
                atomicAdd(&lds[(v >> 1) - wbase], (v & 1) ? 0x10000u : 1u);
        }
        __syncthreads();
        for (int w = t; w < nw; w += 512) partial[wbase + w] = lds[w];
        __syncthreads();
    }
}

// sum partials -> rowcnt (unpacked) and dinv (from col degree + self loop)
__global__ __launch_bounds__(256) void k_hist_reduce(const unsigned* __restrict__ Prow,
                                                     const unsigned* __restrict__ Pcol,
                                                     unsigned* __restrict__ rowcnt,
                                                     float* __restrict__ dinv) {
    int w = blockIdx.x * 256 + threadIdx.x;
    if (w >= HW) return;
    unsigned sr = 0, sc = 0;
    for (int b = 0; b < HG; b++) {
        sr += Prow[(size_t)b * HW + w];
        sc += Pcol[(size_t)b * HW + w];
    }
    rowcnt[2 * w] = sr & 0xffffu;
    rowcnt[2 * w + 1] = sr >> 16;
    dinv[2 * w] = rsqrtf((float)((sc & 0xffffu) + 1u));
    dinv[2 * w + 1] = rsqrtf((float)((sc >> 16) + 1u));
}

// ---------------- scans + CSR fill ----------------
__global__ void k_scan_block(const unsigned* __restrict__ cnt, unsigned* __restrict__ excl,
                             unsigned* __restrict__ partials) {
    __shared__ unsigned s[256];
    int t = threadIdx.x;
    int i = blockIdx.x * 256 + t;
    unsigned v = (i < NN) ? cnt[i] : 0u;
    s[t] = v;
    __syncthreads();
    for (int off = 1; off < 256; off <<= 1) {
        unsigned x = (t >= off) ? s[t - off] : 0u;
        __syncthreads();
        s[t] += x;
        __syncthreads();
    }
    if (i < NN) excl[i] = s[t] - v;
    if (t == 255) partials[blockIdx.x] = s[255];
}

__global__ void k_scan_partials(unsigned* __restrict__ partials, int n) {
    __shared__ unsigned s[256];
    int t = threadIdx.x;
    unsigned v = (t < n) ? partials[t] : 0u;
    s[t] = v;
    __syncthreads();
    for (int off = 1; off < 256; off <<= 1) {
        unsigned x = (t >= off) ? s[t - off] : 0u;
        __syncthreads();
        s[t] += x;
        __syncthreads();
    }
    if (t < n) partials[t] = s[t] - v;
}

__global__ void k_scan_add(unsigned* __restrict__ rowptr, const unsigned* __restrict__ partials,
                           unsigned* __restrict__ cursor) {
    int i = blockIdx.x * blockDim.x + threadIdx.x;
    if (i < NN) {
        unsigned p = rowptr[i] + partials[i >> 8];
        rowptr[i] = p;
        cursor[i] = p;
    }
    if (i == 0) rowptr[NN] = NE;
}

__global__ void k_fill(const int* __restrict__ row, const int* __restrict__ col,
                       unsigned* __restrict__ cursor, int* __restrict__ colidx) {
    for (int e = blockIdx.x * blockDim.x + threadIdx.x; e < NE; e += gridDim.x * blockDim.x) {
        int r = row[e];
        unsigned p = atomicAdd(&cursor[r], 1u);
        colidx[p] = col[e];
    }
}

// ---------------- fused input prep: cast x (dinv-scaled) + weight transpose ----------------
__global__ void k_prep(const float* __restrict__ x, const float* __restrict__ dinv,
                       ushort* __restrict__ xs,
                       const float* __restrict__ W1, const float* __restrict__ W2,
                       const float* __restrict__ W3,
                       ushort* __restrict__ Wt1, ushort* __restrict__ Wt2,
                       ushort* __restrict__ Wt3) {
    int b = blockIdx.x, t = threadIdx.x;
    if (b < 6250) {
        int i = b * 256 + t;  // over N*128/4 = 1.6M exactly
        int row = i >> 5;
        float d = dinv[row];
        float4 v = ((const float4*)x)[i];
        ushort4 o;
        o.x = f2bf(v.x * d); o.y = f2bf(v.y * d); o.z = f2bf(v.z * d); o.w = f2bf(v.w * d);
        ((ushort4*)xs)[i] = o;
    } else {
        int i = (b - 6250) * 256 + t;
        if (i < 128 * 256) { int k = i / 256, n = i % 256; Wt1[n * 128 + k] = f2bf(W1[i]); }
        if (i < 256 * 256) { int k = i / 256, n = i % 256; Wt2[n * 256 + k] = f2bf(W2[i]); }
        if (i < 48 * 256)  { int n = i / 256, k = i % 256;
                             Wt3[i] = (n < OUT_DIM) ? f2bf(W3[k * OUT_DIM + n]) : (ushort)0; }
    }
}

// ---------------- layer-1 aggregation on raw features (128-dim) ----------------
__global__ __launch_bounds__(64) void k_agg_x(const ushort* __restrict__ xs,
                                              const unsigned* __restrict__ rowptr,
                                              const int* __restrict__ colidx,
                                              const float* __restrict__ dinv,
                                              ushort* __restrict__ Xa) {
    int r = blockIdx.x;
    int t = threadIdx.x;
    const unsigned* Xv = (const unsigned*)xs;
    unsigned y = Xv[(size_t)r * 64 + t];
    float a0 = bflo(y), a1 = bfhi(y);
    unsigned e0 = rowptr[r], e1 = rowptr[r + 1];
    unsigned e = e0;
    for (; e + 4 <= e1; e += 4) {
        int c0 = colidx[e], c1 = colidx[e + 1], c2 = colidx[e + 2], c3 = colidx[e + 3];
        unsigned v0 = Xv[(size_t)c0 * 64 + t];
        unsigned v1 = Xv[(size_t)c1 * 64 + t];
        unsigned v2 = Xv[(size_t)c2 * 64 + t];
        unsigned v3 = Xv[(size_t)c3 * 64 + t];
        a0 += bflo(v0) + bflo(v1) + bflo(v2) + bflo(v3);
        a1 += bfhi(v0) + bfhi(v1) + bfhi(v2) + bfhi(v3);
    }
    for (; e < e1; e++) {
        unsigned v = Xv[(size_t)colidx[e] * 64 + t];
        a0 += bflo(v); a1 += bfhi(v);
    }
    float dr = dinv[r];
    ((unsigned*)Xa)[(size_t)r * 64 + t] = (unsigned)f2bf(dr * a0) | ((unsigned)f2bf(dr * a1) << 16);
}

// ---------------- MFMA GEMM 1: H[N x 256](fp32) = Xa[N x 128](bf16) @ Wt1^T ----------------
template <int K>
__global__ __launch_bounds__(256) void k_gemm1(const ushort* __restrict__ A,
                                               const ushort* __restrict__ Bt,
                                               float* __restrict__ H) {
    constexpr int BK = 32;
    constexpr int LD = 40;
    __shared__ ushort sA[64 * LD];
    __shared__ ushort sB[128 * LD];
    int t = threadIdx.x;
    int wave = t >> 6, lane = t & 63;
    int quad = lane >> 4, m15 = lane & 15;
    long r0 = (long)blockIdx.x * 64;
    int n0 = blockIdx.y * 128;

    f32x4 acc[8];
#pragma unroll
    for (int i = 0; i < 8; i++) { acc[i][0] = 0.f; acc[i][1] = 0.f; acc[i][2] = 0.f; acc[i][3] = 0.f; }

    for (int k0 = 0; k0 < K; k0 += BK) {
        {
            int row = t >> 2, seg = (t & 3) * 8;
            long gr = r0 + row;
            uint4 v = make_uint4(0, 0, 0, 0);
            if (gr < NN) v = *(const uint4*)(A + gr * K + k0 + seg);
            *(uint4*)(sA + row * LD + seg) = v;
        }
        {
            int n = t >> 1, seg = (t & 1) * 16;
            const uint4* src = (const uint4*)(Bt + (long)(n0 + n) * K + k0 + seg);
            uint4 b0 = src[0], b1 = src[1];
            *(uint4*)(sB + n * LD + seg) = b0;
            *(uint4*)(sB + n * LD + seg + 8) = b1;
        }
        __syncthreads();
        short8 a = *(const short8*)(sA + (wave * 16 + m15) * LD + quad * 8);
#pragma unroll
        for (int ct = 0; ct < 8; ct++) {
            short8 b = *(const short8*)(sB + (ct * 16 + m15) * LD + quad * 8);
            acc[ct] = __builtin_amdgcn_mfma_f32_16x16x32_bf16(a, b, acc[ct], 0, 0, 0);
        }
        __syncthreads();
    }
    long rowbase = r0 + wave * 16 + quad * 4;
#pragma unroll
    for (int ct = 0; ct < 8; ct++) {
        int col = n0 + ct * 16 + m15;
#pragma unroll
        for (int rg = 0; rg < 4; rg++) {
            long gr = rowbase + rg;
            if (gr < NN) H[gr * 256 + col] = acc[ct][rg];
        }
    }
}

// ---------------- MFMA GEMM 2: Ys2 = bf16( dinv * (relu(bn(H)) @ Wt2^T) ) ----------------
__global__ __launch_bounds__(256) void k_gemm2(const float* __restrict__ H,
                                               const float* __restrict__ bn,
                                               const ushort* __restrict__ Bt,
                                               const float* __restrict__ dinv,
                                               ushort* __restrict__ Y) {
    constexpr int K = 256, BK = 32, LD = 40;
    __shared__ ushort sA[64 * LD];
    __shared__ ushort sB[128 * LD];
    int t = threadIdx.x;
    int wave = t >> 6, lane = t & 63;
    int quad = lane >> 4, m15 = lane & 15;
    long r0 = (long)blockIdx.x * 64;
    int n0 = blockIdx.y * 128;

    f32x4 acc[8];
#pragma unroll
    for (int i = 0; i < 8; i++) { acc[i][0] = 0.f; acc[i][1] = 0.f; acc[i][2] = 0.f; acc[i][3] = 0.f; }

    for (int k0 = 0; k0 < K; k0 += BK) {
        {
            int row = t >> 2, seg = (t & 3) * 8;
            long gr = r0 + row;
            float4 h0 = make_float4(0, 0, 0, 0), h1 = h0;
            if (gr < NN) {
                h0 = *(const float4*)(H + gr * 256 + k0 + seg);
                h1 = *(const float4*)(H + gr * 256 + k0 + seg + 4);
            }
            float4 sc0 = *(const float4*)(bn + 512 + k0 + seg);
            float4 sc1 = *(const float4*)(bn + 512 + k0 + seg + 4);
            float4 sf0 = *(const float4*)(bn + 768 + k0 + seg);
            float4 sf1 = *(const float4*)(bn + 768 + k0 + seg + 4);
            ushort* dst = sA + row * LD + seg;
            dst[0] = f2bf(fmaxf(h0.x * sc0.x + sf0.x, 0.f));
            dst[1] = f2bf(fmaxf(h0.y * sc0.y + sf0.y, 0.f));
            dst[2] = f2bf(fmaxf(h0.z * sc0.z + sf0.z, 0.f));
            dst[3] = f2bf(fmaxf(h0.w * sc0.w + sf0.w, 0.f));
            dst[4] = f2bf(fmaxf(h1.x * sc1.x + sf1.x, 0.f));
            dst[5] = f2bf(fmaxf(h1.y * sc1.y + sf1.y, 0.f));
            dst[6] = f2bf(fmaxf(h1.z * sc1.z + sf1.z, 0.f));
            dst[7] = f2bf(fmaxf(h1.w * sc1.w + sf1.w, 0.f));
        }
        {
            int n = t >> 1, seg = (t & 1) * 16;
            const uint4* src = (const uint4*)(Bt + (long)(n0 + n) * K + k0 + seg);
            uint4 b0 = src[0], b1 = src[1];
            *(uint4*)(sB + n * LD + seg) = b0;
            *(uint4*)(sB + n * LD + seg + 8) = b1;
        }
        __syncthreads();
        short8 a = *(const short8*)(sA + (wave * 16 + m15) * LD + quad * 8);
#pragma unroll
        for (int ct = 0; ct < 8; ct++) {
            short8 b = *(const short8*)(sB + (ct * 16 + m15) * LD + quad * 8);
            acc[ct] = __builtin_amdgcn_mfma_f32_16x16x32_bf16(a, b, acc[ct], 0, 0, 0);
        }
        __syncthreads();
    }
    long rowbase = r0 + wave * 16 + quad * 4;
#pragma unroll
    for (int ct = 0; ct < 8; ct++) {
        int col = n0 + ct * 16 + m15;
#pragma unroll
        for (int rg = 0; rg < 4; rg++) {
            long gr = rowbase + rg;
            if (gr < NN) Y[gr * 256 + col] = f2bf(dinv[gr] * acc[ct][rg]);
        }
    }
}

// ---------------- MFMA GEMM 3: Ys3 (stride 64, bf16) = dinv * (relu(bn(H)) @ Wt3^T) ----------------
__global__ __launch_bounds__(256) void k_gemm3(const float* __restrict__ H,
                                               const float* __restrict__ bn,
                                               const ushort* __restrict__ Wt3,
                                               const float* __restrict__ dinv,
                                               ushort* __restrict__ Y) {
    constexpr int LD = 264;
    __shared__ ushort sA[64 * LD];
    __shared__ ushort sB[48 * LD];
    int t = threadIdx.x;
    int wave = t >> 6, lane = t & 63;
    int quad = lane >> 4, m15 = lane & 15;
    long r0 = (long)blockIdx.x * 64;

    for (int idx = t; idx < 48 * 16; idx += 256) {
        int n = idx >> 4, s = (idx & 15) * 16;
        const uint4* src = (const uint4*)(Wt3 + n * 256 + s);
        *(uint4*)(sB + n * LD + s) = src[0];
        *(uint4*)(sB + n * LD + s + 8) = src[1];
    }
    {
        int row = t >> 2;
        long gr = r0 + row;
        for (int s8 = 0; s8 < 8; s8++) {
            int seg = s8 * 32 + (t & 3) * 8;
            float4 h0 = make_float4(0, 0, 0, 0), h1 = h0;
            if (gr < NN) {
                h0 = *(const float4*)(H + gr * 256 + seg);
                h1 = *(const float4*)(H + gr * 256 + seg + 4);
            }
            float4 sc0 = *(const float4*)(bn + 512 + seg);
            float4 sc1 = *(const float4*)(bn + 512 + seg + 4);
            float4 sf0 = *(const float4*)(bn + 768 + seg);
            float4 sf1 = *(const float4*)(bn + 768 + seg + 4);
            ushort* dst = sA + row * LD + seg;
            dst[0] = f2bf(fmaxf(h0.x * sc0.x + sf0.x, 0.f));
            dst[1] = f2bf(fmaxf(h0.y * sc0.y + sf0.y, 0.f));
            dst[2] = f2bf(fmaxf(h0.z * sc0.z + sf0.z, 0.f));
            dst[3] = f2bf(fmaxf(h0.w * sc0.w + sf0.w, 0.f));
            dst[4] = f2bf(fmaxf(h1.x * sc1.x + sf1.x, 0.f));
            dst[5] = f2bf(fmaxf(h1.y * sc1.y + sf1.y, 0.f));
            dst[6] = f2bf(fmaxf(h1.z * sc1.z + sf1.z, 0.f));
            dst[7] = f2bf(fmaxf(h1.w * sc1.w + sf1.w, 0.f));
        }
    }
    __syncthreads();

    f32x4 acc[3];
#pragma unroll
    for (int i = 0; i < 3; i++) { acc[i][0] = 0.f; acc[i][1] = 0.f; acc[i][2] = 0.f; acc[i][3] = 0.f; }
#pragma unroll
    for (int k0 = 0; k0 < 256; k0 += 32) {
        short8 a = *(const short8*)(sA + (wave * 16 + m15) * LD + k0 + quad * 8);
#pragma unroll
        for (int ct = 0; ct < 3; ct++) {
            short8 b = *(const short8*)(sB + (ct * 16 + m15) * LD + k0 + quad * 8);
            acc[ct] = __builtin_amdgcn_mfma_f32_16x16x32_bf16(a, b, acc[ct], 0, 0, 0);
        }
    }
    long rowbase = r0 + wave * 16 + quad * 4;
#pragma unroll
    for (int ct = 0; ct < 3; ct++) {
        int col = ct * 16 + m15;
#pragma unroll
        for (int rg = 0; rg < 4; rg++) {
            long gr = rowbase + rg;
            if (gr < NN) Y[gr * 64 + col] = f2bf(dinv[gr] * acc[ct][rg]);
        }
    }
}

// ---------------- layer-2 aggregation (256-dim bf16, pre-scaled, unroll-4) ----------------
__global__ __launch_bounds__(64) void k_agg_hid(const ushort* __restrict__ Y,
                                                const unsigned* __restrict__ rowptr,
                                                const int* __restrict__ colidx,
                                                const float* __restrict__ dinv,
                                                float* __restrict__ H) {
    int r = blockIdx.x;
    int t = threadIdx.x;
    const uint2* Yv = (const uint2*)Y;
    uint2 y = Yv[(size_t)r * 64 + t];
    float a0 = bflo(y.x), a1 = bfhi(y.x), a2 = bflo(y.y), a3 = bfhi(y.y);
    unsigned e0 = rowptr[r], e1 = rowptr[r + 1];
    unsigned e = e0;
    for (; e + 4 <= e1; e += 4) {
        int c0 = colidx[e], c1 = colidx[e + 1], c2 = colidx[e + 2], c3 = colidx[e + 3];
        uint2 v0 = Yv[(size_t)c0 * 64 + t];
        uint2 v1 = Yv[(size_t)c1 * 64 + t];
        uint2 v2 = Yv[(size_t)c2 * 64 + t];
        uint2 v3 = Yv[(size_t)c3 * 64 + t];
        a0 += bflo(v0.x) + bflo(v1.x) + bflo(v2.x) + bflo(v3.x);
        a1 += bfhi(v0.x) + bfhi(v1.x) + bfhi(v2.x) + bfhi(v3.x);
        a2 += bflo(v0.y) + bflo(v1.y) + bflo(v2.y) + bflo(v3.y);
        a3 += bfhi(v0.y) + bfhi(v1.y) + bfhi(v2.y) + bfhi(v3.y);
    }
    for (; e < e1; e++) {
        uint2 v = Yv[(size_t)colidx[e] * 64 + t];
        a0 += bflo(v.x); a1 += bfhi(v.x);
        a2 += bflo(v.y); a3 += bfhi(v.y);
    }
    float dr = dinv[r];
    float4 o;
    o.x = dr * a0; o.y = dr * a1; o.z = dr * a2; o.w = dr * a3;
    ((float4*)H)[(size_t)r * 64 + t] = o;
}

// ---------------- layer-3 aggregation + bias + log_softmax (unroll-4) ----------------
__global__ __launch_bounds__(64) void k_agg_lsm(const ushort* __restrict__ Y,
                                                const unsigned* __restrict__ rowptr,
                                                const int* __restrict__ colidx,
                                                const float* __restrict__ dinv,
                                                const float* __restrict__ b3,
                                                float* __restrict__ out) {
    int r = blockIdx.x;
    int t = threadIdx.x;
    bool act = t < OUT_DIM;
    float acc = act ? bflo((unsigned)Y[(size_t)r * 64 + t]) : 0.f;
    unsigned e0 = rowptr[r], e1 = rowptr[r + 1];
    unsigned e = e0;
    for (; e + 4 <= e1; e += 4) {
        int c0 = colidx[e], c1 = colidx[e + 1], c2 = colidx[e + 2], c3 = colidx[e + 3];
        if (act) {
            float v0 = bflo((unsigned)Y[(size_t)c0 * 64 + t]);
            float v1 = bflo((unsigned)Y[(size_t)c1 * 64 + t]);
            float v2 = bflo((unsigned)Y[(size_t)c2 * 64 + t]);
            float v3 = bflo((unsigned)Y[(size_t)c3 * 64 + t]);
            acc += v0 + v1 + v2 + v3;
        }
    }
    for (; e < e1; e++) {
        if (act) acc += bflo((unsigned)Y[(size_t)colidx[e] * 64 + t]);
    }
    float o = act ? (dinv[r] * acc + b3[t]) : 0.f;
    float m = act ? o : -1e30f;
#pragma unroll
    for (int d = 1; d < 64; d <<= 1) m = fmaxf(m, __shfl_xor(m, d, 64));
    float ex = act ? expf(o - m) : 0.f;
#pragma unroll
    for (int d = 1; d < 64; d <<= 1) ex += __shfl_xor(ex, d, 64);
    float ls = logf(ex) + m;
    if (act) out[(size_t)r * OUT_DIM + t] = o - ls;
}

// ---------------- BatchNorm (partials, no atomics / no memset) ----------------
__global__ __launch_bounds__(256) void k_bn_stats(const float* __restrict__ H,
                                                  float* __restrict__ bnpart) {
    int t = threadIdx.x;
    int b = blockIdx.x;
    int rows_per = (NN + gridDim.x - 1) / gridDim.x;
    int r0 = b * rows_per;
    int r1 = r0 + rows_per; if (r1 > NN) r1 = NN;
    float s = 0.f, sq = 0.f;
    for (int r = r0; r < r1; r++) {
        float v = H[(size_t)r * 256 + t];
        s += v; sq += v * v;
    }
    bnpart[(size_t)b * 512 + t] = s;
    bnpart[(size_t)b * 512 + 256 + t] = sq;
}

__global__ __launch_bounds__(256) void k_bn_final(const float* __restrict__ bnpart,
                                                  const float* __restrict__ gamma,
                                                  const float* __restrict__ beta,
                                                  float* __restrict__ bn) {
    int t = threadIdx.x;
    float s = 0.f, sq = 0.f;
    for (int b = 0; b < 256; b++) {
        s += bnpart[(size_t)b * 512 + t];
        sq += bnpart[(size_t)b * 512 + 256 + t];
    }
    float mu = s * (1.f / NN);
    float var = sq * (1.f / NN) - mu * mu;
    float rstd = rsqrtf(var + BN_EPS);
    float g = gamma[t] * rstd;
    bn[512 + t] = g;
    bn[768 + t] = beta[t] - mu * g;
}

// ---------------- launch ----------------

extern "C" void kernel_launch(void* const* d_in, const int* in_sizes, int n_in,
                              void* d_out, int out_size, void* d_ws, size_t ws_size,
                              hipStream_t stream) {
    const float* x     = (const float*)d_in[0];
    const int*   erow  = (const int*)d_in[1];
    const int*   ecol  = ((const int*)d_in[1]) + NE;
    const float* W1    = (const float*)d_in[2];
    const float* W2    = (const float*)d_in[4];
    const float* W3    = (const float*)d_in[6];
    const float* b3    = (const float*)d_in[7];
    const float* gamma = (const float*)d_in[8];
    const float* beta  = (const float*)d_in[9];
    float* out = (float*)d_out;

    char* ws = (char*)d_ws;
    size_t off = 0;
    auto alloc = [&](size_t bytes) -> void* {
        void* p = ws + off;
        off = (off + bytes + 255) & ~(size_t)255;
        return p;
    };
    float*    dinv     = (float*)alloc(NN * 4);
    unsigned* rowcnt   = (unsigned*)alloc(NN * 4);
    unsigned* rowptr   = (unsigned*)alloc((NN + 1) * 4);
    unsigned* cursor   = (unsigned*)alloc(NN * 4);
    unsigned* partials = (unsigned*)alloc(256 * 4);
    int*      colidx   = (int*)alloc((size_t)NE * 4);
    float*    bn       = (float*)alloc(1024 * 4);
    float*    bnpart   = (float*)alloc(256 * 512 * 4);
    ushort*   Wt1      = (ushort*)alloc(128 * 256 * 2);
    ushort*   Wt2      = (ushort*)alloc(256 * 256 * 2);
    ushort*   Wt3      = (ushort*)alloc(48 * 256 * 2);
    ushort*   xs       = (ushort*)alloc((size_t)NN * IN_DIM * 2);
    ushort*   Xa       = (ushort*)alloc((size_t)NN * IN_DIM * 2);
    float*    H        = (float*)alloc((size_t)NN * HID * 4);
    ushort*   Ys2      = (ushort*)alloc((size_t)NN * HID * 2);
    ushort*   Ys3      = (ushort*)alloc((size_t)NN * 64 * 2);

    // histogram partials alias H (51.2 MB; hist done before gemm1 writes H)
    unsigned* Prow = (unsigned*)H;
    unsigned* Pcol = Prow + (size_t)HG * HW;

    const int nscan = (NN + 255) / 256;

    // --- preprocessing: no global atomics in histogram path ---
    k_hist_lds<<<dim3(HG, 2), 512, 0, stream>>>(erow, ecol, Prow, Pcol);
    k_hist_reduce<<<(HW + 255) / 256, 256, 0, stream>>>(Prow, Pcol, rowcnt, dinv);
    k_scan_block<<<nscan, 256, 0, stream>>>(rowcnt, rowptr, partials);
    k_scan_partials<<<1, 256, 0, stream>>>(partials, nscan);
    k_scan_add<<<nscan, 256, 0, stream>>>(rowptr, partials, cursor);
    k_fill<<<2048, 256, 0, stream>>>(erow, ecol, cursor, colidx);
    k_prep<<<6250 + 256, 256, 0, stream>>>(x, dinv, xs, W1, W2, W3, Wt1, Wt2, Wt3);

    dim3 ggrid((NN + 63) / 64, 2);

    // --- layer 1: aggregate-first, then transform ---
    k_agg_x<<<NN, 64, 0, stream>>>(xs, rowptr, colidx, dinv, Xa);
    k_gemm1<IN_DIM><<<ggrid, 256, 0, stream>>>(Xa, Wt1, H);
    k_bn_stats<<<256, 256, 0, stream>>>(H, bnpart);
    k_bn_final<<<1, 256, 0, stream>>>(bnpart, gamma, beta, bn);

    // --- layer 2 ---
    k_gemm2<<<ggrid, 256, 0, stream>>>(H, bn, Wt2, dinv, Ys2);
    k_agg_hid<<<NN, 64, 0, stream>>>(Ys2, rowptr, colidx, dinv, H);
    k_bn_stats<<<256, 256, 0, stream>>>(H, bnpart);
    k_bn_final<<<1, 256, 0, stream>>>(bnpart, gamma, beta, bn);

    // --- layer 3 ---
    k_gemm3<<<(NN + 63) / 64, 256, 0, stream>>>(H, bn, Wt3, dinv, Ys3);
    k_agg_lsm<<<NN, 64, 0, stream>>>(Ys3, rowptr, colidx, dinv, b3, out);
}

// Round 5
// 459.769 us; speedup vs baseline: 1.9972x; 1.0591x over previous
//
#include <hip/hip_runtime.h>
#include <math.h>

#define NN 50000
#define NE 800000
#define IN_DIM 128
#define HID 256
#define OUT_DIM 40
#define BN_EPS 1e-5f

#define HG 128          // histogram blocks (col-degree)
#define HW 25000        // packed words (2 nodes/word)
#define HPASS 12800     // words per LDS pass

#define NBK 196         // row buckets (256 rows each)
#define PB 256          // partition blocks
#define EPB (NE / PB)   // 3125 edges per partition block

typedef __attribute__((ext_vector_type(8))) short short8;
typedef __attribute__((ext_vector_type(4))) float f32x4;

__device__ __forceinline__ ushort f2bf(float f) {
    union { float f; unsigned u; } v; v.f = f;
    unsigned r = v.u + 0x7fffu + ((v.u >> 16) & 1u);
    return (ushort)(r >> 16);
}
__device__ __forceinline__ float bflo(unsigned u) {
    union { unsigned a; float f; } v; v.a = u << 16; return v.f;
}
__device__ __forceinline__ float bfhi(unsigned u) {
    union { unsigned a; float f; } v; v.a = u & 0xffff0000u; return v.f;
}

// ---------------- col-degree histogram via LDS -> dinv ----------------
__global__ __launch_bounds__(512) void k_hist_col(const int* __restrict__ ecol,
                                                  unsigned* __restrict__ Pcol) {
    __shared__ unsigned lds[HPASS];
    int t = threadIdx.x;
    int b = blockIdx.x;
    unsigned* partial = Pcol + (size_t)b * HW;
    int e0 = b * (NE / HG), e1 = e0 + (NE / HG);
#pragma unroll
    for (int pass = 0; pass < 2; pass++) {
        int wbase = pass ? HPASS : 0;
        int wend = pass ? HW : HPASS;
        int nw = wend - wbase;
        for (int w = t; w < HPASS; w += 512) lds[w] = 0u;
        __syncthreads();
        int vlo = wbase * 2, vhi = wend * 2;
        for (int e = e0 + t; e < e1; e += 512) {
            int v = ecol[e];
            if (v >= vlo && v < vhi)
                atomicAdd(&lds[(v >> 1) - wbase], (v & 1) ? 0x10000u : 1u);
        }
        __syncthreads();
        for (int w = t; w < nw; w += 512) partial[wbase + w] = lds[w];
        __syncthreads();
    }
}

__global__ __launch_bounds__(256) void k_hist_reduce(const unsigned* __restrict__ Pcol,
                                                     float* __restrict__ dinv) {
    int w = blockIdx.x * 256 + threadIdx.x;
    if (w >= HW) return;
    unsigned sc = 0;
    for (int b = 0; b < HG; b++) sc += Pcol[(size_t)b * HW + w];
    dinv[2 * w] = rsqrtf((float)((sc & 0xffffu) + 1u));
    dinv[2 * w + 1] = rsqrtf((float)((sc >> 16) + 1u));
}

// ---------------- bucketed CSR build ----------------
// part1: per-(block,bucket) counts
__global__ __launch_bounds__(256) void k_part1(const int* __restrict__ erow,
                                               unsigned* __restrict__ cnt) {
    __shared__ unsigned c[NBK];
    int t = threadIdx.x, b = blockIdx.x;
    for (int i = t; i < NBK; i += 256) c[i] = 0u;
    __syncthreads();
    int e0 = b * EPB;
    for (int i = t; i < EPB; i += 256) atomicAdd(&c[((unsigned)erow[e0 + i]) >> 8], 1u);
    __syncthreads();
    for (int i = t; i < NBK; i += 256) cnt[b * NBK + i] = c[i];
}

// part2: bucket starts + per-(block,bucket) write offsets
__global__ __launch_bounds__(256) void k_part2(const unsigned* __restrict__ cnt,
                                               unsigned* __restrict__ off,
                                               unsigned* __restrict__ bstart) {
    __shared__ unsigned s[256];
    int t = threadIdx.x;
    unsigned tot = 0;
    if (t < NBK) for (int b = 0; b < PB; b++) tot += cnt[b * NBK + t];
    s[t] = tot;
    __syncthreads();
    for (int o = 1; o < 256; o <<= 1) {
        unsigned x = (t >= o) ? s[t - o] : 0u;
        __syncthreads();
        s[t] += x;
        __syncthreads();
    }
    unsigned base = s[t] - tot;
    if (t < NBK) bstart[t] = base;
    if (t == NBK - 1) bstart[NBK] = base + tot;
    if (t < NBK) {
        unsigned run = base;
        for (int b = 0; b < PB; b++) { off[b * NBK + t] = run; run += cnt[b * NBK + t]; }
    }
}

// part3: scatter edges into bucket-grouped buffer
__global__ __launch_bounds__(256) void k_part3(const int* __restrict__ erow,
                                               const int* __restrict__ ecol,
                                               const unsigned* __restrict__ off,
                                               int2* __restrict__ ebuf) {
    __shared__ unsigned c[NBK];
    int t = threadIdx.x, b = blockIdx.x;
    for (int i = t; i < NBK; i += 256) c[i] = off[b * NBK + i];
    __syncthreads();
    int e0 = b * EPB;
    for (int i = t; i < EPB; i += 256) {
        int r = erow[e0 + i], cc = ecol[e0 + i];
        unsigned p = atomicAdd(&c[((unsigned)r) >> 8], 1u);
        ebuf[p] = make_int2(r, cc);
    }
}

// part4: per-bucket row counts -> rowptr (scan) -> colidx fill (L2-local)
__global__ __launch_bounds__(256) void k_part4(const int2* __restrict__ ebuf,
                                               const unsigned* __restrict__ bstart,
                                               unsigned* __restrict__ rowptr,
                                               int* __restrict__ colidx) {
    __shared__ unsigned rc[256], cur[256], s[256];
    int t = threadIdx.x, b = blockIdx.x;
    unsigned ebase = bstart[b], ecnt = bstart[b + 1] - ebase;
    rc[t] = 0u;
    __syncthreads();
    for (unsigned i = t; i < ecnt; i += 256) atomicAdd(&rc[ebuf[ebase + i].x & 255], 1u);
    __syncthreads();
    unsigned v = rc[t];
    s[t] = v;
    __syncthreads();
    for (int o = 1; o < 256; o <<= 1) {
        unsigned x = (t >= o) ? s[t - o] : 0u;
        __syncthreads();
        s[t] += x;
        __syncthreads();
    }
    unsigned excl = s[t] - v;
    int row = (b << 8) + t;
    if (row < NN) rowptr[row] = ebase + excl;
    cur[t] = ebase + excl;
    if (b == 0 && t == 0) rowptr[NN] = NE;
    __syncthreads();
    for (unsigned i = t; i < ecnt; i += 256) {
        int2 e = ebuf[ebase + i];
        unsigned p = atomicAdd(&cur[e.x & 255], 1u);
        colidx[p] = e.y;
    }
}

// ---------------- fused input prep: cast x (dinv-scaled) + weight transpose ----------------
__global__ void k_prep(const float* __restrict__ x, const float* __restrict__ dinv,
                       ushort* __restrict__ xs,
                       const float* __restrict__ W1, const float* __restrict__ W2,
                       const float* __restrict__ W3,
                       ushort* __restrict__ Wt1, ushort* __restrict__ Wt2,
                       ushort* __restrict__ Wt3) {
    int b = blockIdx.x, t = threadIdx.x;
    if (b < 6250) {
        int i = b * 256 + t;
        int row = i >> 5;
        float d = dinv[row];
        float4 v = ((const float4*)x)[i];
        ushort4 o;
        o.x = f2bf(v.x * d); o.y = f2bf(v.y * d); o.z = f2bf(v.z * d); o.w = f2bf(v.w * d);
        ((ushort4*)xs)[i] = o;
    } else {
        int i = (b - 6250) * 256 + t;
        if (i < 128 * 256) { int k = i / 256, n = i % 256; Wt1[n * 128 + k] = f2bf(W1[i]); }
        if (i < 256 * 256) { int k = i / 256, n = i % 256; Wt2[n * 256 + k] = f2bf(W2[i]); }
        if (i < 48 * 256)  { int n = i / 256, k = i % 256;
                             Wt3[i] = (n < OUT_DIM) ? f2bf(W3[k * OUT_DIM + n]) : (ushort)0; }
    }
}

// ---------------- layer-1 aggregation on raw features (128-dim, unroll-8) ----------------
__global__ __launch_bounds__(64) void k_agg_x(const ushort* __restrict__ xs,
                                              const unsigned* __restrict__ rowptr,
                                              const int* __restrict__ colidx,
                                              const float* __restrict__ dinv,
                                              ushort* __restrict__ Xa) {
    int r = blockIdx.x;
    int t = threadIdx.x;
    const unsigned* Xv = (const unsigned*)xs;
    unsigned y = Xv[(size_t)r * 64 + t];
    float a0 = bflo(y), a1 = bfhi(y);
    unsigned e0 = rowptr[r], e1 = rowptr[r + 1];
    unsigned e = e0;
    for (; e + 8 <= e1; e += 8) {
        unsigned v0 = Xv[(size_t)colidx[e] * 64 + t];
        unsigned v1 = Xv[(size_t)colidx[e + 1] * 64 + t];
        unsigned v2 = Xv[(size_t)colidx[e + 2] * 64 + t];
        unsigned v3 = Xv[(size_t)colidx[e + 3] * 64 + t];
        unsigned v4 = Xv[(size_t)colidx[e + 4] * 64 + t];
        unsigned v5 = Xv[(size_t)colidx[e + 5] * 64 + t];
        unsigned v6 = Xv[(size_t)colidx[e + 6] * 64 + t];
        unsigned v7 = Xv[(size_t)colidx[e + 7] * 64 + t];
        a0 += bflo(v0) + bflo(v1) + bflo(v2) + bflo(v3) + bflo(v4) + bflo(v5) + bflo(v6) + bflo(v7);
        a1 += bfhi(v0) + bfhi(v1) + bfhi(v2) + bfhi(v3) + bfhi(v4) + bfhi(v5) + bfhi(v6) + bfhi(v7);
    }
    for (; e < e1; e++) {
        unsigned v = Xv[(size_t)colidx[e] * 64 + t];
        a0 += bflo(v); a1 += bfhi(v);
    }
    float dr = dinv[r];
    ((unsigned*)Xa)[(size_t)r * 64 + t] = (unsigned)f2bf(dr * a0) | ((unsigned)f2bf(dr * a1) << 16);
}

// ---------------- MFMA GEMM 1: H[N x 256](fp32) = Xa[N x 128](bf16) @ Wt1^T ----------------
template <int K>
__global__ __launch_bounds__(256) void k_gemm1(const ushort* __restrict__ A,
                                               const ushort* __restrict__ Bt,
                                               float* __restrict__ H) {
    constexpr int BK = 32;
    constexpr int LD = 40;
    __shared__ ushort sA[64 * LD];
    __shared__ ushort sB[128 * LD];
    int t = threadIdx.x;
    int wave = t >> 6, lane = t & 63;
    int quad = lane >> 4, m15 = lane & 15;
    long r0 = (long)blockIdx.x * 64;
    int n0 = blockIdx.y * 128;

    f32x4 acc[8];
#pragma unroll
    for (int i = 0; i < 8; i++) { acc[i][0] = 0.f; acc[i][1] = 0.f; acc[i][2] = 0.f; acc[i][3] = 0.f; }

    for (int k0 = 0; k0 < K; k0 += BK) {
        {
            int row = t >> 2, seg = (t & 3) * 8;
            long gr = r0 + row;
            uint4 v = make_uint4(0, 0, 0, 0);
            if (gr < NN) v = *(const uint4*)(A + gr * K + k0 + seg);
            *(uint4*)(sA + row * LD + seg) = v;
        }
        {
            int n = t >> 1, seg = (t & 1) * 16;
            const uint4* src = (const uint4*)(Bt + (long)(n0 + n) * K + k0 + seg);
            uint4 b0 = src[0], b1 = src[1];
            *(uint4*)(sB + n * LD + seg) = b0;
            *(uint4*)(sB + n * LD + seg + 8) = b1;
        }
        __syncthreads();
        short8 a = *(const short8*)(sA + (wave * 16 + m15) * LD + quad * 8);
#pragma unroll
        for (int ct = 0; ct < 8; ct++) {
            short8 b = *(const short8*)(sB + (ct * 16 + m15) * LD + quad * 8);
            acc[ct] = __builtin_amdgcn_mfma_f32_16x16x32_bf16(a, b, acc[ct], 0, 0, 0);
        }
        __syncthreads();
    }
    long rowbase = r0 + wave * 16 + quad * 4;
#pragma unroll
    for (int ct = 0; ct < 8; ct++) {
        int col = n0 + ct * 16 + m15;
#pragma unroll
        for (int rg = 0; rg < 4; rg++) {
            long gr = rowbase + rg;
            if (gr < NN) H[gr * 256 + col] = acc[ct][rg];
        }
    }
}

// ---------------- MFMA GEMM 2: Ys2 = bf16( dinv * (relu(bn(H)) @ Wt2^T) ) ----------------
__global__ __launch_bounds__(256) void k_gemm2(const float* __restrict__ H,
                                               const float* __restrict__ bn,
                                               const ushort* __restrict__ Bt,
                                               const float* __restrict__ dinv,
                                               ushort* __restrict__ Y) {
    constexpr int K = 256, BK = 32, LD = 40;
    __shared__ ushort sA[64 * LD];
    __shared__ ushort sB[128 * LD];
    int t = threadIdx.x;
    int wave = t >> 6, lane = t & 63;
    int quad = lane >> 4, m15 = lane & 15;
    long r0 = (long)blockIdx.x * 64;
    int n0 = blockIdx.y * 128;

    f32x4 acc[8];
#pragma unroll
    for (int i = 0; i < 8; i++) { acc[i][0] = 0.f; acc[i][1] = 0.f; acc[i][2] = 0.f; acc[i][3] = 0.f; }

    for (int k0 = 0; k0 < K; k0 += BK) {
        {
            int row = t >> 2, seg = (t & 3) * 8;
            long gr = r0 + row;
            float4 h0 = make_float4(0, 0, 0, 0), h1 = h0;
            if (gr < NN) {
                h0 = *(const float4*)(H + gr * 256 + k0 + seg);
                h1 = *(const float4*)(H + gr * 256 + k0 + seg + 4);
            }
            float4 sc0 = *(const float4*)(bn + 512 + k0 + seg);
            float4 sc1 = *(const float4*)(bn + 512 + k0 + seg + 4);
            float4 sf0 = *(const float4*)(bn + 768 + k0 + seg);
            float4 sf1 = *(const float4*)(bn + 768 + k0 + seg + 4);
            ushort* dst = sA + row * LD + seg;
            dst[0] = f2bf(fmaxf(h0.x * sc0.x + sf0.x, 0.f));
            dst[1] = f2bf(fmaxf(h0.y * sc0.y + sf0.y, 0.f));
            dst[2] = f2bf(fmaxf(h0.z * sc0.z + sf0.z, 0.f));
            dst[3] = f2bf(fmaxf(h0.w * sc0.w + sf0.w, 0.f));
            dst[4] = f2bf(fmaxf(h1.x * sc1.x + sf1.x, 0.f));
            dst[5] = f2bf(fmaxf(h1.y * sc1.y + sf1.y, 0.f));
            dst[6] = f2bf(fmaxf(h1.z * sc1.z + sf1.z, 0.f));
            dst[7] = f2bf(fmaxf(h1.w * sc1.w + sf1.w, 0.f));
        }
        {
            int n = t >> 1, seg = (t & 1) * 16;
            const uint4* src = (const uint4*)(Bt + (long)(n0 + n) * K + k0 + seg);
            uint4 b0 = src[0], b1 = src[1];
            *(uint4*)(sB + n * LD + seg) = b0;
            *(uint4*)(sB + n * LD + seg + 8) = b1;
        }
        __syncthreads();
        short8 a = *(const short8*)(sA + (wave * 16 + m15) * LD + quad * 8);
#pragma unroll
        for (int ct = 0; ct < 8; ct++) {
            short8 b = *(const short8*)(sB + (ct * 16 + m15) * LD + quad * 8);
            acc[ct] = __builtin_amdgcn_mfma_f32_16x16x32_bf16(a, b, acc[ct], 0, 0, 0);
        }
        __syncthreads();
    }
    long rowbase = r0 + wave * 16 + quad * 4;
#pragma unroll
    for (int ct = 0; ct < 8; ct++) {
        int col = n0 + ct * 16 + m15;
#pragma unroll
        for (int rg = 0; rg < 4; rg++) {
            long gr = rowbase + rg;
            if (gr < NN) Y[gr * 256 + col] = f2bf(dinv[gr] * acc[ct][rg]);
        }
    }
}

// ---------------- MFMA GEMM 3: Ys3 (stride 64, bf16) = dinv * (relu(bn(H)) @ Wt3^T) ----------------
__global__ __launch_bounds__(256) void k_gemm3(const float* __restrict__ H,
                                               const float* __restrict__ bn,
                                               const ushort* __restrict__ Wt3,
                                               const float* __restrict__ dinv,
                                               ushort* __restrict__ Y) {
    constexpr int LD = 264;
    __shared__ ushort sA[64 * LD];
    __shared__ ushort sB[48 * LD];
    int t = threadIdx.x;
    int wave = t >> 6, lane = t & 63;
    int quad = lane >> 4, m15 = lane & 15;
    long r0 = (long)blockIdx.x * 64;

    for (int idx = t; idx < 48 * 16; idx += 256) {
        int n = idx >> 4, s = (idx & 15) * 16;
        const uint4* src = (const uint4*)(Wt3 + n * 256 + s);
        *(uint4*)(sB + n * LD + s) = src[0];
        *(uint4*)(sB + n * LD + s + 8) = src[1];
    }
    {
        int row = t >> 2;
        long gr = r0 + row;
        for (int s8 = 0; s8 < 8; s8++) {
            int seg = s8 * 32 + (t & 3) * 8;
            float4 h0 = make_float4(0, 0, 0, 0), h1 = h0;
            if (gr < NN) {
                h0 = *(const float4*)(H + gr * 256 + seg);
                h1 = *(const float4*)(H + gr * 256 + seg + 4);
            }
            float4 sc0 = *(const float4*)(bn + 512 + seg);
            float4 sc1 = *(const float4*)(bn + 512 + seg + 4);
            float4 sf0 = *(const float4*)(bn + 768 + seg);
            float4 sf1 = *(const float4*)(bn + 768 + seg + 4);
            ushort* dst = sA + row * LD + seg;
            dst[0] = f2bf(fmaxf(h0.x * sc0.x + sf0.x, 0.f));
            dst[1] = f2bf(fmaxf(h0.y * sc0.y + sf0.y, 0.f));
            dst[2] = f2bf(fmaxf(h0.z * sc0.z + sf0.z, 0.f));
            dst[3] = f2bf(fmaxf(h0.w * sc0.w + sf0.w, 0.f));
            dst[4] = f2bf(fmaxf(h1.x * sc1.x + sf1.x, 0.f));
            dst[5] = f2bf(fmaxf(h1.y * sc1.y + sf1.y, 0.f));
            dst[6] = f2bf(fmaxf(h1.z * sc1.z + sf1.z, 0.f));
            dst[7] = f2bf(fmaxf(h1.w * sc1.w + sf1.w, 0.f));
        }
    }
    __syncthreads();

    f32x4 acc[3];
#pragma unroll
    for (int i = 0; i < 3; i++) { acc[i][0] = 0.f; acc[i][1] = 0.f; acc[i][2] = 0.f; acc[i][3] = 0.f; }
#pragma unroll
    for (int k0 = 0; k0 < 256; k0 += 32) {
        short8 a = *(const short8*)(sA + (wave * 16 + m15) * LD + k0 + quad * 8);
#pragma unroll
        for (int ct = 0; ct < 3; ct++) {
            short8 b = *(const short8*)(sB + (ct * 16 + m15) * LD + k0 + quad * 8);
            acc[ct] = __builtin_amdgcn_mfma_f32_16x16x32_bf16(a, b, acc[ct], 0, 0, 0);
        }
    }
    long rowbase = r0 + wave * 16 + quad * 4;
#pragma unroll
    for (int ct = 0; ct < 3; ct++) {
        int col = ct * 16 + m15;
#pragma unroll
        for (int rg = 0; rg < 4; rg++) {
            long gr = rowbase + rg;
            if (gr < NN) Y[gr * 64 + col] = f2bf(dinv[gr] * acc[ct][rg]);
        }
    }
}

// ---------------- layer-2 aggregation (256-dim bf16, pre-scaled, unroll-8) ----------------
__global__ __launch_bounds__(64) void k_agg_hid(const ushort* __restrict__ Y,
                                                const unsigned* __restrict__ rowptr,
                                                const int* __restrict__ colidx,
                                                const float* __restrict__ dinv,
                                                float* __restrict__ H) {
    int r = blockIdx.x;
    int t = threadIdx.x;
    const uint2* Yv = (const uint2*)Y;
    uint2 y = Yv[(size_t)r * 64 + t];
    float a0 = bflo(y.x), a1 = bfhi(y.x), a2 = bflo(y.y), a3 = bfhi(y.y);
    unsigned e0 = rowptr[r], e1 = rowptr[r + 1];
    unsigned e = e0;
    for (; e + 8 <= e1; e += 8) {
        uint2 v0 = Yv[(size_t)colidx[e] * 64 + t];
        uint2 v1 = Yv[(size_t)colidx[e + 1] * 64 + t];
        uint2 v2 = Yv[(size_t)colidx[e + 2] * 64 + t];
        uint2 v3 = Yv[(size_t)colidx[e + 3] * 64 + t];
        uint2 v4 = Yv[(size_t)colidx[e + 4] * 64 + t];
        uint2 v5 = Yv[(size_t)colidx[e + 5] * 64 + t];
        uint2 v6 = Yv[(size_t)colidx[e + 6] * 64 + t];
        uint2 v7 = Yv[(size_t)colidx[e + 7] * 64 + t];
        a0 += bflo(v0.x) + bflo(v1.x) + bflo(v2.x) + bflo(v3.x)
            + bflo(v4.x) + bflo(v5.x) + bflo(v6.x) + bflo(v7.x);
        a1 += bfhi(v0.x) + bfhi(v1.x) + bfhi(v2.x) + bfhi(v3.x)
            + bfhi(v4.x) + bfhi(v5.x) + bfhi(v6.x) + bfhi(v7.x);
        a2 += bflo(v0.y) + bflo(v1.y) + bflo(v2.y) + bflo(v3.y)
            + bflo(v4.y) + bflo(v5.y) + bflo(v6.y) + bflo(v7.y);
        a3 += bfhi(v0.y) + bfhi(v1.y) + bfhi(v2.y) + bfhi(v3.y)
            + bfhi(v4.y) + bfhi(v5.y) + bfhi(v6.y) + bfhi(v7.y);
    }
    for (; e < e1; e++) {
        uint2 v = Yv[(size_t)colidx[e] * 64 + t];
        a0 += bflo(v.x); a1 += bfhi(v.x);
        a2 += bflo(v.y); a3 += bfhi(v.y);
    }
    float dr = dinv[r];
    float4 o;
    o.x = dr * a0; o.y = dr * a1; o.z = dr * a2; o.w = dr * a3;
    ((float4*)H)[(size_t)r * 64 + t] = o;
}

// ---------------- layer-3 aggregation + bias + log_softmax ----------------
__global__ __launch_bounds__(64) void k_agg_lsm(const ushort* __restrict__ Y,
                                                const unsigned* __restrict__ rowptr,
                                                const int* __restrict__ colidx,
                                                const float* __restrict__ dinv,
                                                const float* __restrict__ b3,
                                                float* __restrict__ out) {
    int r = blockIdx.x;
    int t = threadIdx.x;
    bool act = t < OUT_DIM;
    float acc = act ? bflo((unsigned)Y[(size_t)r * 64 + t]) : 0.f;
    unsigned e0 = rowptr[r], e1 = rowptr[r + 1];
    unsigned e = e0;
    for (; e + 4 <= e1; e += 4) {
        int c0 = colidx[e], c1 = colidx[e + 1], c2 = colidx[e + 2], c3 = colidx[e + 3];
        if (act) {
            acc += bflo((unsigned)Y[(size_t)c0 * 64 + t]) + bflo((unsigned)Y[(size_t)c1 * 64 + t])
                 + bflo((unsigned)Y[(size_t)c2 * 64 + t]) + bflo((unsigned)Y[(size_t)c3 * 64 + t]);
        }
    }
    for (; e < e1; e++) {
        if (act) acc += bflo((unsigned)Y[(size_t)colidx[e] * 64 + t]);
    }
    float o = act ? (dinv[r] * acc + b3[t]) : 0.f;
    float m = act ? o : -1e30f;
#pragma unroll
    for (int d = 1; d < 64; d <<= 1) m = fmaxf(m, __shfl_xor(m, d, 64));
    float ex = act ? expf(o - m) : 0.f;
#pragma unroll
    for (int d = 1; d < 64; d <<= 1) ex += __shfl_xor(ex, d, 64);
    float ls = logf(ex) + m;
    if (act) out[(size_t)r * OUT_DIM + t] = o - ls;
}

// ---------------- BatchNorm (partials, no atomics / no memset) ----------------
__global__ __launch_bounds__(256) void k_bn_stats(const float* __restrict__ H,
                                                  float* __restrict__ bnpart) {
    int t = threadIdx.x;
    int b = blockIdx.x;
    int rows_per = (NN + gridDim.x - 1) / gridDim.x;
    int r0 = b * rows_per;
    int r1 = r0 + rows_per; if (r1 > NN) r1 = NN;
    float s = 0.f, sq = 0.f;
    for (int r = r0; r < r1; r++) {
        float v = H[(size_t)r * 256 + t];
        s += v; sq += v * v;
    }
    bnpart[(size_t)b * 512 + t] = s;
    bnpart[(size_t)b * 512 + 256 + t] = sq;
}

__global__ __launch_bounds__(256) void k_bn_final(const float* __restrict__ bnpart,
                                                  const float* __restrict__ gamma,
                                                  const float* __restrict__ beta,
                                                  float* __restrict__ bn) {
    int t = threadIdx.x;
    float s = 0.f, sq = 0.f;
    for (int b = 0; b < 256; b++) {
        s += bnpart[(size_t)b * 512 + t];
        sq += bnpart[(size_t)b * 512 + 256 + t];
    }
    float mu = s * (1.f / NN);
    float var = sq * (1.f / NN) - mu * mu;
    float rstd = rsqrtf(var + BN_EPS);
    float g = gamma[t] * rstd;
    bn[512 + t] = g;
    bn[768 + t] = beta[t] - mu * g;
}

// ---------------- launch ----------------

extern "C" void kernel_launch(void* const* d_in, const int* in_sizes, int n_in,
                              void* d_out, int out_size, void* d_ws, size_t ws_size,
                              hipStream_t stream) {
    const float* x     = (const float*)d_in[0];
    const int*   erow  = (const int*)d_in[1];
    const int*   ecol  = ((const int*)d_in[1]) + NE;
    const float* W1    = (const float*)d_in[2];
    const float* W2    = (const float*)d_in[4];
    const float* W3    = (const float*)d_in[6];
    const float* b3    = (const float*)d_in[7];
    const float* gamma = (const float*)d_in[8];
    const float* beta  = (const float*)d_in[9];
    float* out = (float*)d_out;

    char* ws = (char*)d_ws;
    size_t off = 0;
    auto alloc = [&](size_t bytes) -> void* {
        void* p = ws + off;
        off = (off + bytes + 255) & ~(size_t)255;
        return p;
    };
    float*    dinv     = (float*)alloc(NN * 4);
    unsigned* rowptr   = (unsigned*)alloc((NN + 1) * 4);
    int*      colidx   = (int*)alloc((size_t)NE * 4);
    float*    bn       = (float*)alloc(1024 * 4);
    float*    bnpart   = (float*)alloc(256 * 512 * 4);
    unsigned* cnt      = (unsigned*)alloc((size_t)PB * NBK * 4);
    unsigned* boff     = (unsigned*)alloc((size_t)PB * NBK * 4);
    unsigned* bstart   = (unsigned*)alloc((NBK + 1) * 4);
    ushort*   Wt1      = (ushort*)alloc(128 * 256 * 2);
    ushort*   Wt2      = (ushort*)alloc(256 * 256 * 2);
    ushort*   Wt3      = (ushort*)alloc(48 * 256 * 2);
    ushort*   xs       = (ushort*)alloc((size_t)NN * IN_DIM * 2);
    ushort*   Xa       = (ushort*)alloc((size_t)NN * IN_DIM * 2);
    float*    H        = (float*)alloc((size_t)NN * HID * 4);
    ushort*   Ys2      = (ushort*)alloc((size_t)NN * HID * 2);
    ushort*   Ys3      = (ushort*)alloc((size_t)NN * 64 * 2);

    // aliases into H (51.2 MB), all dead before gemm1 writes H:
    unsigned* Pcol = (unsigned*)H;                              // 12.8 MB
    int2*     ebuf = (int2*)((char*)H + (size_t)16 * 1024 * 1024);  // 6.4 MB

    // --- preprocessing ---
    k_hist_col<<<HG, 512, 0, stream>>>(ecol, Pcol);
    k_hist_reduce<<<(HW + 255) / 256, 256, 0, stream>>>(Pcol, dinv);
    k_part1<<<PB, 256, 0, stream>>>(erow, cnt);
    k_part2<<<1, 256, 0, stream>>>(cnt, boff, bstart);
    k_part3<<<PB, 256, 0, stream>>>(erow, ecol, boff, ebuf);
    k_part4<<<NBK, 256, 0, stream>>>(ebuf, bstart, rowptr, colidx);
    k_prep<<<6250 + 256, 256, 0, stream>>>(x, dinv, xs, W1, W2, W3, Wt1, Wt2, Wt3);

    dim3 ggrid((NN + 63) / 64, 2);

    // --- layer 1: aggregate-first, then transform ---
    k_agg_x<<<NN, 64, 0, stream>>>(xs, rowptr, colidx, dinv, Xa);
    k_gemm1<IN_DIM><<<ggrid, 256, 0, stream>>>(Xa, Wt1, H);
    k_bn_stats<<<256, 256, 0, stream>>>(H, bnpart);
    k_bn_final<<<1, 256, 0, stream>>>(bnpart, gamma, beta, bn);

    // --- layer 2 ---
    k_gemm2<<<ggrid, 256, 0, stream>>>(H, bn, Wt2, dinv, Ys2);
    k_agg_hid<<<NN, 64, 0, stream>>>(Ys2, rowptr, colidx, dinv, H);
    k_bn_stats<<<256, 256, 0, stream>>>(H, bnpart);
    k_bn_final<<<1, 256, 0, stream>>>(bnpart, gamma, beta, bn);

    // --- layer 3 ---
    k_gemm3<<<(NN + 63) / 64, 256, 0, stream>>>(H, bn, Wt3, dinv, Ys3);
    k_agg_lsm<<<NN, 64, 0, stream>>>(Ys3, rowptr, colidx, dinv, b3, out);
}

// Round 7
// 404.991 us; speedup vs baseline: 2.2673x; 1.1353x over previous
//
#include <hip/hip_runtime.h>
#include <math.h>

#define NN 50000
#define NE 800000
#define IN_DIM 128
#define HID 256
#define OUT_DIM 40
#define BN_EPS 1e-5f

#define HG 128          // histogram blocks (col-degree)
#define HW 25000        // packed words (2 nodes/word)
#define HPASS 12800     // words per LDS pass

#define NBK 196         // row buckets (256 rows each)
#define PB 256          // partition blocks
#define EPB (NE / PB)   // 3125 edges per partition block

typedef __attribute__((ext_vector_type(8))) short short8;
typedef __attribute__((ext_vector_type(4))) float f32x4;
typedef __attribute__((ext_vector_type(2))) float f32x2;

__device__ __forceinline__ ushort f2bf(float f) {
    union { float f; unsigned u; } v; v.f = f;
    unsigned r = v.u + 0x7fffu + ((v.u >> 16) & 1u);
    return (ushort)(r >> 16);
}
__device__ __forceinline__ float bflo(unsigned u) {
    union { unsigned a; float f; } v; v.a = u << 16; return v.f;
}
__device__ __forceinline__ float bfhi(unsigned u) {
    union { unsigned a; float f; } v; v.a = u & 0xffff0000u; return v.f;
}
// fp8 e4m3 (OCP) via HW converts — word-select must be a literal constant
__device__ __forceinline__ f32x2 fp8_dec_lo(int v) {
    return __builtin_amdgcn_cvt_pk_f32_fp8(v, false);
}
__device__ __forceinline__ f32x2 fp8_dec_hi(int v) {
    return __builtin_amdgcn_cvt_pk_f32_fp8(v, true);
}
__device__ __forceinline__ int fp8_enc_lo(float a, float b, int old) {
    return __builtin_amdgcn_cvt_pk_fp8_f32(a, b, old, false);
}
__device__ __forceinline__ int fp8_enc_hi(float a, float b, int old) {
    return __builtin_amdgcn_cvt_pk_fp8_f32(a, b, old, true);
}

// ================ P1: col-degree LDS histogram (blocks 0..HG) + row-bucket counts (HG..HG+PB) ================
__global__ __launch_bounds__(512) void k_p1(const int* __restrict__ erow,
                                            const int* __restrict__ ecol,
                                            unsigned* __restrict__ Pcol,
                                            unsigned* __restrict__ cnt) {
    __shared__ unsigned lds[HPASS];
    int t = threadIdx.x;
    int b = blockIdx.x;
    if (b < HG) {
        unsigned* partial = Pcol + (size_t)b * HW;
        int e0 = b * (NE / HG), e1 = e0 + (NE / HG);
#pragma unroll
        for (int pass = 0; pass < 2; pass++) {
            int wbase = pass ? HPASS : 0;
            int wend = pass ? HW : HPASS;
            int nw = wend - wbase;
            for (int w = t; w < HPASS; w += 512) lds[w] = 0u;
            __syncthreads();
            int vlo = wbase * 2, vhi = wend * 2;
            for (int e = e0 + t; e < e1; e += 512) {
                int v = ecol[e];
                if (v >= vlo && v < vhi)
                    atomicAdd(&lds[(v >> 1) - wbase], (v & 1) ? 0x10000u : 1u);
            }
            __syncthreads();
            for (int w = t; w < nw; w += 512) partial[wbase + w] = lds[w];
            __syncthreads();
        }
    } else {
        int bb = b - HG;
        for (int i = t; i < NBK; i += 512) lds[i] = 0u;
        __syncthreads();
        int e0 = bb * EPB;
        for (int i = t; i < EPB; i += 512) atomicAdd(&lds[((unsigned)erow[e0 + i]) >> 8], 1u);
        __syncthreads();
        for (int i = t; i < NBK; i += 512) cnt[bb * NBK + i] = lds[i];
    }
}

// ================ P2: hist reduce -> dinv (blocks 0..97) + bucket scan/offsets (block 98) ================
__global__ __launch_bounds__(256) void k_p2(const unsigned* __restrict__ Pcol,
                                            float* __restrict__ dinv,
                                            const unsigned* __restrict__ cnt,
                                            unsigned* __restrict__ off,
                                            unsigned* __restrict__ bstart) {
    int t = threadIdx.x;
    if (blockIdx.x < 98) {
        int w = blockIdx.x * 256 + t;
        if (w >= HW) return;
        unsigned sc = 0;
        for (int b = 0; b < HG; b++) sc += Pcol[(size_t)b * HW + w];
        dinv[2 * w] = rsqrtf((float)((sc & 0xffffu) + 1u));
        dinv[2 * w + 1] = rsqrtf((float)((sc >> 16) + 1u));
    } else {
        __shared__ unsigned s[256];
        unsigned tot = 0;
        if (t < NBK) for (int b = 0; b < PB; b++) tot += cnt[b * NBK + t];
        s[t] = tot;
        __syncthreads();
        for (int o = 1; o < 256; o <<= 1) {
            unsigned x = (t >= o) ? s[t - o] : 0u;
            __syncthreads();
            s[t] += x;
            __syncthreads();
        }
        unsigned base = s[t] - tot;
        if (t < NBK) bstart[t] = base;
        if (t == NBK - 1) bstart[NBK] = base + tot;
        if (t < NBK) {
            unsigned run = base;
            for (int b = 0; b < PB; b++) { off[b * NBK + t] = run; run += cnt[b * NBK + t]; }
        }
    }
}

// ================ P3: edge scatter into buckets (blocks 0..PB) + input prep (rest) ================
__global__ __launch_bounds__(256) void k_p3(const int* __restrict__ erow,
                                            const int* __restrict__ ecol,
                                            const unsigned* __restrict__ off,
                                            int2* __restrict__ ebuf,
                                            const float* __restrict__ x,
                                            const float* __restrict__ dinv,
                                            uchar* __restrict__ xs8,
                                            const float* __restrict__ W1,
                                            const float* __restrict__ W2,
                                            const float* __restrict__ W3,
                                            ushort* __restrict__ Wt1,
                                            ushort* __restrict__ Wt2,
                                            ushort* __restrict__ Wt3) {
    int t = threadIdx.x, b = blockIdx.x;
    if (b < PB) {
        __shared__ unsigned c[NBK];
        for (int i = t; i < NBK; i += 256) c[i] = off[b * NBK + i];
        __syncthreads();
        int e0 = b * EPB;
        for (int i = t; i < EPB; i += 256) {
            int r = erow[e0 + i], cc = ecol[e0 + i];
            unsigned p = atomicAdd(&c[((unsigned)r) >> 8], 1u);
            ebuf[p] = make_int2(r, cc);
        }
    } else if (b < PB + 6250) {
        int i = (b - PB) * 256 + t;   // over N*128/4 = 1.6M exactly
        int row = i >> 5;
        float d = dinv[row];
        float4 v = ((const float4*)x)[i];
        int p = fp8_enc_lo(v.x * d, v.y * d, 0);
        p = fp8_enc_hi(v.z * d, v.w * d, p);
        ((int*)xs8)[i] = p;
    } else {
        int i = (b - PB - 6250) * 256 + t;
        if (i < 128 * 256) { int k = i / 256, n = i % 256; Wt1[n * 128 + k] = f2bf(W1[i]); }
        if (i < 256 * 256) { int k = i / 256, n = i % 256; Wt2[n * 256 + k] = f2bf(W2[i]); }
        if (i < 48 * 256)  { int n = i / 256, k = i % 256;
                             Wt3[i] = (n < OUT_DIM) ? f2bf(W3[k * OUT_DIM + n]) : (ushort)0; }
    }
}

// ================ P4: per-bucket row counts -> rowptr -> colidx fill ================
__global__ __launch_bounds__(256) void k_part4(const int2* __restrict__ ebuf,
                                               const unsigned* __restrict__ bstart,
                                               unsigned* __restrict__ rowptr,
                                               int* __restrict__ colidx) {
    __shared__ unsigned rc[256], cur[256], s[256];
    int t = threadIdx.x, b = blockIdx.x;
    unsigned ebase = bstart[b], ecnt = bstart[b + 1] - ebase;
    rc[t] = 0u;
    __syncthreads();
    for (unsigned i = t; i < ecnt; i += 256) atomicAdd(&rc[ebuf[ebase + i].x & 255], 1u);
    __syncthreads();
    unsigned v = rc[t];
    s[t] = v;
    __syncthreads();
    for (int o = 1; o < 256; o <<= 1) {
        unsigned x = (t >= o) ? s[t - o] : 0u;
        __syncthreads();
        s[t] += x;
        __syncthreads();
    }
    unsigned excl = s[t] - v;
    int row = (b << 8) + t;
    if (row < NN) rowptr[row] = ebase + excl;
    cur[t] = ebase + excl;
    if (b == 0 && t == 0) rowptr[NN] = NE;
    __syncthreads();
    for (unsigned i = t; i < ecnt; i += 256) {
        int2 e = ebuf[ebase + i];
        unsigned p = atomicAdd(&cur[e.x & 255], 1u);
        colidx[p] = e.y;
    }
}

// ================ layer-1 aggregation on fp8 features (128-dim, unroll-8) ================
__global__ __launch_bounds__(64) void k_agg_x(const uchar* __restrict__ xs8,
                                              const unsigned* __restrict__ rowptr,
                                              const int* __restrict__ colidx,
                                              const float* __restrict__ dinv,
                                              ushort* __restrict__ Xa) {
    int r = blockIdx.x;
    int t = threadIdx.x;  // 64 lanes x 2 fp8 cols
    const ushort* Xv = (const ushort*)xs8;
    f32x2 sf = fp8_dec_lo((int)Xv[(size_t)r * 64 + t]);
    float a0 = sf[0], a1 = sf[1];
    unsigned e0 = rowptr[r], e1 = rowptr[r + 1];
    unsigned e = e0;
    for (; e + 8 <= e1; e += 8) {
        int v0 = Xv[(size_t)colidx[e] * 64 + t];
        int v1 = Xv[(size_t)colidx[e + 1] * 64 + t];
        int v2 = Xv[(size_t)colidx[e + 2] * 64 + t];
        int v3 = Xv[(size_t)colidx[e + 3] * 64 + t];
        int v4 = Xv[(size_t)colidx[e + 4] * 64 + t];
        int v5 = Xv[(size_t)colidx[e + 5] * 64 + t];
        int v6 = Xv[(size_t)colidx[e + 6] * 64 + t];
        int v7 = Xv[(size_t)colidx[e + 7] * 64 + t];
        f32x2 f0 = fp8_dec_lo(v0), f1 = fp8_dec_lo(v1);
        f32x2 f2 = fp8_dec_lo(v2), f3 = fp8_dec_lo(v3);
        f32x2 f4 = fp8_dec_lo(v4), f5 = fp8_dec_lo(v5);
        f32x2 f6 = fp8_dec_lo(v6), f7 = fp8_dec_lo(v7);
        a0 += f0[0] + f1[0] + f2[0] + f3[0] + f4[0] + f5[0] + f6[0] + f7[0];
        a1 += f0[1] + f1[1] + f2[1] + f3[1] + f4[1] + f5[1] + f6[1] + f7[1];
    }
    for (; e < e1; e++) {
        f32x2 f = fp8_dec_lo((int)Xv[(size_t)colidx[e] * 64 + t]);
        a0 += f[0]; a1 += f[1];
    }
    float dr = dinv[r];
    ((unsigned*)Xa)[(size_t)r * 64 + t] = (unsigned)f2bf(dr * a0) | ((unsigned)f2bf(dr * a1) << 16);
}

// ================ MFMA GEMM 1: H16[N x 256](bf16) = Xa[N x 128](bf16) @ Wt1^T ================
template <int K>
__global__ __launch_bounds__(256) void k_gemm1(const ushort* __restrict__ A,
                                               const ushort* __restrict__ Bt,
                                               ushort* __restrict__ H16) {
    constexpr int BK = 32;
    constexpr int LD = 40;
    __shared__ ushort sA[64 * LD];
    __shared__ ushort sB[128 * LD];
    int t = threadIdx.x;
    int wave = t >> 6, lane = t & 63;
    int quad = lane >> 4, m15 = lane & 15;
    long r0 = (long)blockIdx.x * 64;
    int n0 = blockIdx.y * 128;

    f32x4 acc[8];
#pragma unroll
    for (int i = 0; i < 8; i++) { acc[i][0] = 0.f; acc[i][1] = 0.f; acc[i][2] = 0.f; acc[i][3] = 0.f; }

    for (int k0 = 0; k0 < K; k0 += BK) {
        {
            int row = t >> 2, seg = (t & 3) * 8;
            long gr = r0 + row;
            uint4 v = make_uint4(0, 0, 0, 0);
            if (gr < NN) v = *(const uint4*)(A + gr * K + k0 + seg);
            *(uint4*)(sA + row * LD + seg) = v;
        }
        {
            int n = t >> 1, seg = (t & 1) * 16;
            const uint4* src = (const uint4*)(Bt + (long)(n0 + n) * K + k0 + seg);
            uint4 b0 = src[0], b1 = src[1];
            *(uint4*)(sB + n * LD + seg) = b0;
            *(uint4*)(sB + n * LD + seg + 8) = b1;
        }
        __syncthreads();
        short8 a = *(const short8*)(sA + (wave * 16 + m15) * LD + quad * 8);
#pragma unroll
        for (int ct = 0; ct < 8; ct++) {
            short8 b = *(const short8*)(sB + (ct * 16 + m15) * LD + quad * 8);
            acc[ct] = __builtin_amdgcn_mfma_f32_16x16x32_bf16(a, b, acc[ct], 0, 0, 0);
        }
        __syncthreads();
    }
    long rowbase = r0 + wave * 16 + quad * 4;
#pragma unroll
    for (int ct = 0; ct < 8; ct++) {
        int col = n0 + ct * 16 + m15;
#pragma unroll
        for (int rg = 0; rg < 4; rg++) {
            long gr = rowbase + rg;
            if (gr < NN) H16[gr * 256 + col] = f2bf(acc[ct][rg]);
        }
    }
}

// BN+ReLU stage of 8 bf16 cols from H16 row into LDS
__device__ __forceinline__ void bn_stage8(const ushort* __restrict__ Hrow, bool valid,
                                          const float* __restrict__ bn, int col0,
                                          ushort* __restrict__ dst) {
    uint4 hv = make_uint4(0, 0, 0, 0);
    if (valid) hv = *(const uint4*)(Hrow + col0);
    float f[8] = { bflo(hv.x), bfhi(hv.x), bflo(hv.y), bfhi(hv.y),
                   bflo(hv.z), bfhi(hv.z), bflo(hv.w), bfhi(hv.w) };
#pragma unroll
    for (int j = 0; j < 8; j++)
        dst[j] = f2bf(fmaxf(f[j] * bn[512 + col0 + j] + bn[768 + col0 + j], 0.f));
}

// ================ MFMA GEMM 2: Ys2(fp8) = fp8( dinv * (relu(bn(H16)) @ Wt2^T) ) ================
__global__ __launch_bounds__(256) void k_gemm2(const ushort* __restrict__ H16,
                                               const float* __restrict__ bn,
                                               const ushort* __restrict__ Bt,
                                               const float* __restrict__ dinv,
                                               uchar* __restrict__ Y8) {
    constexpr int K = 256, BK = 32, LD = 40;
    __shared__ ushort sA[64 * LD];
    __shared__ ushort sB[128 * LD];
    int t = threadIdx.x;
    int wave = t >> 6, lane = t & 63;
    int quad = lane >> 4, m15 = lane & 15;
    long r0 = (long)blockIdx.x * 64;
    int n0 = blockIdx.y * 128;

    f32x4 acc[8];
#pragma unroll
    for (int i = 0; i < 8; i++) { acc[i][0] = 0.f; acc[i][1] = 0.f; acc[i][2] = 0.f; acc[i][3] = 0.f; }

    for (int k0 = 0; k0 < K; k0 += BK) {
        {
            int row = t >> 2, seg = (t & 3) * 8;
            long gr = r0 + row;
            bn_stage8(H16 + gr * 256, gr < NN, bn, k0 + seg, sA + row * LD + seg);
        }
        {
            int n = t >> 1, seg = (t & 1) * 16;
            const uint4* src = (const uint4*)(Bt + (long)(n0 + n) * K + k0 + seg);
            uint4 b0 = src[0], b1 = src[1];
            *(uint4*)(sB + n * LD + seg) = b0;
            *(uint4*)(sB + n * LD + seg + 8) = b1;
        }
        __syncthreads();
        short8 a = *(const short8*)(sA + (wave * 16 + m15) * LD + quad * 8);
#pragma unroll
        for (int ct = 0; ct < 8; ct++) {
            short8 b = *(const short8*)(sB + (ct * 16 + m15) * LD + quad * 8);
            acc[ct] = __builtin_amdgcn_mfma_f32_16x16x32_bf16(a, b, acc[ct], 0, 0, 0);
        }
        __syncthreads();
    }
    long rowbase = r0 + wave * 16 + quad * 4;
    float dv[4];
#pragma unroll
    for (int rg = 0; rg < 4; rg++) dv[rg] = (rowbase + rg < NN) ? dinv[rowbase + rg] : 0.f;
#pragma unroll
    for (int ct = 0; ct < 8; ct++) {
        int col = n0 + ct * 16 + m15;
#pragma unroll
        for (int rg = 0; rg < 4; rg++) {
            long gr = rowbase + rg;
            if (gr < NN) {
                int p = fp8_enc_lo(dv[rg] * acc[ct][rg], 0.f, 0);
                Y8[gr * 256 + col] = (uchar)(p & 0xff);
            }
        }
    }
}

// ================ MFMA GEMM 3: Ys3 (stride 64, bf16) = dinv * (relu(bn(H16)) @ Wt3^T) ================
__global__ __launch_bounds__(256) void k_gemm3(const ushort* __restrict__ H16,
                                               const float* __restrict__ bn,
                                               const ushort* __restrict__ Wt3,
                                               const float* __restrict__ dinv,
                                               ushort* __restrict__ Y) {
    constexpr int LD = 264;
    __shared__ ushort sA[64 * LD];
    __shared__ ushort sB[48 * LD];
    int t = threadIdx.x;
    int wave = t >> 6, lane = t & 63;
    int quad = lane >> 4, m15 = lane & 15;
    long r0 = (long)blockIdx.x * 64;

    for (int idx = t; idx < 48 * 16; idx += 256) {
        int n = idx >> 4, s = (idx & 15) * 16;
        const uint4* src = (const uint4*)(Wt3 + n * 256 + s);
        *(uint4*)(sB + n * LD + s) = src[0];
        *(uint4*)(sB + n * LD + s + 8) = src[1];
    }
    {
        int row = t >> 2;
        long gr = r0 + row;
#pragma unroll
        for (int s8 = 0; s8 < 8; s8++) {
            int seg = s8 * 32 + (t & 3) * 8;
            bn_stage8(H16 + gr * 256, gr < NN, bn, seg, sA + row * LD + seg);
        }
    }
    __syncthreads();

    f32x4 acc[3];
#pragma unroll
    for (int i = 0; i < 3; i++) { acc[i][0] = 0.f; acc[i][1] = 0.f; acc[i][2] = 0.f; acc[i][3] = 0.f; }
#pragma unroll
    for (int k0 = 0; k0 < 256; k0 += 32) {
        short8 a = *(const short8*)(sA + (wave * 16 + m15) * LD + k0 + quad * 8);
#pragma unroll
        for (int ct = 0; ct < 3; ct++) {
            short8 b = *(const short8*)(sB + (ct * 16 + m15) * LD + k0 + quad * 8);
            acc[ct] = __builtin_amdgcn_mfma_f32_16x16x32_bf16(a, b, acc[ct], 0, 0, 0);
        }
    }
    long rowbase = r0 + wave * 16 + quad * 4;
#pragma unroll
    for (int ct = 0; ct < 3; ct++) {
        int col = ct * 16 + m15;
#pragma unroll
        for (int rg = 0; rg < 4; rg++) {
            long gr = rowbase + rg;
            if (gr < NN) Y[gr * 64 + col] = f2bf(dinv[gr] * acc[ct][rg]);
        }
    }
}

// ================ layer-2 aggregation: fp8 gather -> bf16 H16 (unroll-8) ================
__global__ __launch_bounds__(64) void k_agg_hid(const uchar* __restrict__ Y8,
                                                const unsigned* __restrict__ rowptr,
                                                const int* __restrict__ colidx,
                                                const float* __restrict__ dinv,
                                                ushort* __restrict__ H16) {
    int r = blockIdx.x;
    int t = threadIdx.x;  // 64 lanes x 4 fp8 cols
    const int* Yv = (const int*)Y8;
    int y = Yv[(size_t)r * 64 + t];
    f32x2 yl = fp8_dec_lo(y), yh = fp8_dec_hi(y);
    float a0 = yl[0], a1 = yl[1], a2 = yh[0], a3 = yh[1];
    unsigned e0 = rowptr[r], e1 = rowptr[r + 1];
    unsigned e = e0;
    for (; e + 8 <= e1; e += 8) {
        int v0 = Yv[(size_t)colidx[e] * 64 + t];
        int v1 = Yv[(size_t)colidx[e + 1] * 64 + t];
        int v2 = Yv[(size_t)colidx[e + 2] * 64 + t];
        int v3 = Yv[(size_t)colidx[e + 3] * 64 + t];
        int v4 = Yv[(size_t)colidx[e + 4] * 64 + t];
        int v5 = Yv[(size_t)colidx[e + 5] * 64 + t];
        int v6 = Yv[(size_t)colidx[e + 6] * 64 + t];
        int v7 = Yv[(size_t)colidx[e + 7] * 64 + t];
        f32x2 l0 = fp8_dec_lo(v0), h0 = fp8_dec_hi(v0);
        f32x2 l1 = fp8_dec_lo(v1), h1 = fp8_dec_hi(v1);
        f32x2 l2 = fp8_dec_lo(v2), h2 = fp8_dec_hi(v2);
        f32x2 l3 = fp8_dec_lo(v3), h3 = fp8_dec_hi(v3);
        f32x2 l4 = fp8_dec_lo(v4), h4 = fp8_dec_hi(v4);
        f32x2 l5 = fp8_dec_lo(v5), h5 = fp8_dec_hi(v5);
        f32x2 l6 = fp8_dec_lo(v6), h6 = fp8_dec_hi(v6);
        f32x2 l7 = fp8_dec_lo(v7), h7 = fp8_dec_hi(v7);
        a0 += l0[0] + l1[0] + l2[0] + l3[0] + l4[0] + l5[0] + l6[0] + l7[0];
        a1 += l0[1] + l1[1] + l2[1] + l3[1] + l4[1] + l5[1] + l6[1] + l7[1];
        a2 += h0[0] + h1[0] + h2[0] + h3[0] + h4[0] + h5[0] + h6[0] + h7[0];
        a3 += h0[1] + h1[1] + h2[1] + h3[1] + h4[1] + h5[1] + h6[1] + h7[1];
    }
    for (; e < e1; e++) {
        int v = Yv[(size_t)colidx[e] * 64 + t];
        f32x2 l = fp8_dec_lo(v), h = fp8_dec_hi(v);
        a0 += l[0]; a1 += l[1]; a2 += h[0]; a3 += h[1];
    }
    float dr = dinv[r];
    uint2 o;
    o.x = (unsigned)f2bf(dr * a0) | ((unsigned)f2bf(dr * a1) << 16);
    o.y = (unsigned)f2bf(dr * a2) | ((unsigned)f2bf(dr * a3) << 16);
    ((uint2*)H16)[(size_t)r * 64 + t] = o;
}

// ================ layer-3 aggregation + bias + log_softmax ================
__global__ __launch_bounds__(64) void k_agg_lsm(const ushort* __restrict__ Y,
                                                const unsigned* __restrict__ rowptr,
                                                const int* __restrict__ colidx,
                                                const float* __restrict__ dinv,
                                                const float* __restrict__ b3,
                                                float* __restrict__ out) {
    int r = blockIdx.x;
    int t = threadIdx.x;
    bool act = t < OUT_DIM;
    float acc = act ? bflo((unsigned)Y[(size_t)r * 64 + t]) : 0.f;
    unsigned e0 = rowptr[r], e1 = rowptr[r + 1];
    unsigned e = e0;
    for (; e + 4 <= e1; e += 4) {
        int c0 = colidx[e], c1 = colidx[e + 1], c2 = colidx[e + 2], c3 = colidx[e + 3];
        if (act) {
            acc += bflo((unsigned)Y[(size_t)c0 * 64 + t]) + bflo((unsigned)Y[(size_t)c1 * 64 + t])
                 + bflo((unsigned)Y[(size_t)c2 * 64 + t]) + bflo((unsigned)Y[(size_t)c3 * 64 + t]);
        }
    }
    for (; e < e1; e++) {
        if (act) acc += bflo((unsigned)Y[(size_t)colidx[e] * 64 + t]);
    }
    float o = act ? (dinv[r] * acc + b3[t]) : 0.f;
    float m = act ? o : -1e30f;
#pragma unroll
    for (int d = 1; d < 64; d <<= 1) m = fmaxf(m, __shfl_xor(m, d, 64));
    float ex = act ? expf(o - m) : 0.f;
#pragma unroll
    for (int d = 1; d < 64; d <<= 1) ex += __shfl_xor(ex, d, 64);
    float ls = logf(ex) + m;
    if (act) out[(size_t)r * OUT_DIM + t] = o - ls;
}

// ================ BatchNorm stats (bf16 H) ================
__global__ __launch_bounds__(256) void k_bn_stats(const ushort* __restrict__ H16,
                                                  float* __restrict__ bnpart) {
    int t = threadIdx.x;
    int b = blockIdx.x;
    int rows_per = (NN + gridDim.x - 1) / gridDim.x;
    int r0 = b * rows_per;
    int r1 = r0 + rows_per; if (r1 > NN) r1 = NN;
    float s = 0.f, sq = 0.f;
    for (int r = r0; r < r1; r++) {
        float v = bflo((unsigned)H16[(size_t)r * 256 + t]);
        s += v; sq += v * v;
    }
    bnpart[(size_t)b * 512 + t] = s;
    bnpart[(size_t)b * 512 + 256 + t] = sq;
}

__global__ __launch_bounds__(256) void k_bn_final(const float* __restrict__ bnpart,
                                                  const float* __restrict__ gamma,
                                                  const float* __restrict__ beta,
                                                  float* __restrict__ bn) {
    int t = threadIdx.x;
    float s = 0.f, sq = 0.f;
    for (int b = 0; b < 256; b++) {
        s += bnpart[(size_t)b * 512 + t];
        sq += bnpart[(size_t)b * 512 + 256 + t];
    }
    float mu = s * (1.f / NN);
    float var = sq * (1.f / NN) - mu * mu;
    float rstd = rsqrtf(var + BN_EPS);
    float g = gamma[t] * rstd;
    bn[512 + t] = g;
    bn[768 + t] = beta[t] - mu * g;
}

// ================ launch ================

extern "C" void kernel_launch(void* const* d_in, const int* in_sizes, int n_in,
                              void* d_out, int out_size, void* d_ws, size_t ws_size,
                              hipStream_t stream) {
    const float* x     = (const float*)d_in[0];
    const int*   erow  = (const int*)d_in[1];
    const int*   ecol  = ((const int*)d_in[1]) + NE;
    const float* W1    = (const float*)d_in[2];
    const float* W2    = (const float*)d_in[4];
    const float* W3    = (const float*)d_in[6];
    const float* b3    = (const float*)d_in[7];
    const float* gamma = (const float*)d_in[8];
    const float* beta  = (const float*)d_in[9];
    float* out = (float*)d_out;

    char* ws = (char*)d_ws;
    size_t off = 0;
    auto alloc = [&](size_t bytes) -> void* {
        void* p = ws + off;
        off = (off + bytes + 255) & ~(size_t)255;
        return p;
    };
    float*    dinv     = (float*)alloc(NN * 4);
    unsigned* rowptr   = (unsigned*)alloc((NN + 1) * 4);
    int*      colidx   = (int*)alloc((size_t)NE * 4);
    float*    bn       = (float*)alloc(1024 * 4);
    float*    bnpart   = (float*)alloc(256 * 512 * 4);
    unsigned* cnt      = (unsigned*)alloc((size_t)PB * NBK * 4);
    unsigned* boff     = (unsigned*)alloc((size_t)PB * NBK * 4);
    unsigned* bstart   = (unsigned*)alloc((NBK + 1) * 4);
    ushort*   Wt1      = (ushort*)alloc(128 * 256 * 2);
    ushort*   Wt2      = (ushort*)alloc(256 * 256 * 2);
    ushort*   Wt3      = (ushort*)alloc(48 * 256 * 2);
    uchar*    xs8      = (uchar*)alloc((size_t)NN * IN_DIM);       // fp8 dinv-scaled x
    ushort*   Xa       = (ushort*)alloc((size_t)NN * IN_DIM * 2);  // aggregated x, bf16
    ushort*   H16      = (ushort*)alloc((size_t)NN * HID * 2);     // conv output, bf16
    uchar*    Ys2      = (uchar*)alloc((size_t)NN * HID);          // fp8 layer-2 transform
    ushort*   Ys3      = (ushort*)alloc((size_t)NN * 64 * 2);      // bf16 layer-3 transform

    // aliases into H16 (25.6 MB), dead before gemm1 writes H16:
    unsigned* Pcol = (unsigned*)H16;                                   // 12.8 MB
    int2*     ebuf = (int2*)((char*)H16 + (size_t)13 * 1024 * 1024);   // 6.4 MB

    // --- preprocessing (merged) ---
    k_p1<<<HG + PB, 512, 0, stream>>>(erow, ecol, Pcol, cnt);
    k_p2<<<99, 256, 0, stream>>>(Pcol, dinv, cnt, boff, bstart);
    k_p3<<<PB + 6250 + 256, 256, 0, stream>>>(erow, ecol, boff, ebuf,
                                              x, dinv, xs8, W1, W2, W3, Wt1, Wt2, Wt3);
    k_part4<<<NBK, 256, 0, stream>>>(ebuf, bstart, rowptr, colidx);

    dim3 ggrid((NN + 63) / 64, 2);

    // --- layer 1: aggregate-first (fp8 gather), then transform ---
    k_agg_x<<<NN, 64, 0, stream>>>(xs8, rowptr, colidx, dinv, Xa);
    k_gemm1<IN_DIM><<<ggrid, 256, 0, stream>>>(Xa, Wt1, H16);
    k_bn_stats<<<256, 256, 0, stream>>>(H16, bnpart);
    k_bn_final<<<1, 256, 0, stream>>>(bnpart, gamma, beta, bn);

    // --- layer 2: BN fused into GEMM staging; fp8 output table ---
    k_gemm2<<<ggrid, 256, 0, stream>>>(H16, bn, Wt2, dinv, Ys2);
    k_agg_hid<<<NN, 64, 0, stream>>>(Ys2, rowptr, colidx, dinv, H16);
    k_bn_stats<<<256, 256, 0, stream>>>(H16, bnpart);
    k_bn_final<<<1, 256, 0, stream>>>(bnpart, gamma, beta, bn);

    // --- layer 3 ---
    k_gemm3<<<(NN + 63) / 64, 256, 0, stream>>>(H16, bn, Wt3, dinv, Ys3);
    k_agg_lsm<<<NN, 64, 0, stream>>>(Ys3, rowptr, colidx, dinv, b3, out);
}

// Round 8
// 322.749 us; speedup vs baseline: 2.8451x; 1.2548x over previous
//
#include <hip/hip_runtime.h>
#include <math.h>

#define NN 50000
#define NE 800000
#define IN_DIM 128
#define HID 256
#define OUT_DIM 40
#define BN_EPS 1e-5f

#define HG 128          // histogram blocks (col-degree)
#define HW 25000        // packed words (2 nodes/word)
#define HPASS 12800     // words per LDS pass

#define NBK 196         // row buckets (256 rows each)
#define PB 256          // partition blocks
#define EPB (NE / PB)   // 3125 edges per partition block

typedef __attribute__((ext_vector_type(8))) short short8;
typedef __attribute__((ext_vector_type(4))) float f32x4;
typedef __attribute__((ext_vector_type(2))) float f32x2;

__device__ __forceinline__ ushort f2bf(float f) {
    union { float f; unsigned u; } v; v.f = f;
    unsigned r = v.u + 0x7fffu + ((v.u >> 16) & 1u);
    return (ushort)(r >> 16);
}
__device__ __forceinline__ float bflo(unsigned u) {
    union { unsigned a; float f; } v; v.a = u << 16; return v.f;
}
__device__ __forceinline__ float bfhi(unsigned u) {
    union { unsigned a; float f; } v; v.a = u & 0xffff0000u; return v.f;
}
// fp8 e4m3 (OCP) via HW converts — word-select must be a literal constant
__device__ __forceinline__ f32x2 fp8_dec_lo(int v) {
    return __builtin_amdgcn_cvt_pk_f32_fp8(v, false);
}
__device__ __forceinline__ f32x2 fp8_dec_hi(int v) {
    return __builtin_amdgcn_cvt_pk_f32_fp8(v, true);
}
__device__ __forceinline__ int fp8_enc_lo(float a, float b, int old) {
    return __builtin_amdgcn_cvt_pk_fp8_f32(a, b, old, false);
}
__device__ __forceinline__ int fp8_enc_hi(float a, float b, int old) {
    return __builtin_amdgcn_cvt_pk_fp8_f32(a, b, old, true);
}

// ================ P1: col-degree LDS histogram (blocks 0..HG) + row-bucket counts (HG..HG+PB) ================
__global__ __launch_bounds__(512) void k_p1(const int* __restrict__ erow,
                                            const int* __restrict__ ecol,
                                            unsigned* __restrict__ Pcol,
                                            unsigned* __restrict__ cnt) {
    __shared__ unsigned lds[HPASS];
    int t = threadIdx.x;
    int b = blockIdx.x;
    if (b < HG) {
        unsigned* partial = Pcol + (size_t)b * HW;
        int e0 = b * (NE / HG), e1 = e0 + (NE / HG);
#pragma unroll
        for (int pass = 0; pass < 2; pass++) {
            int wbase = pass ? HPASS : 0;
            int wend = pass ? HW : HPASS;
            int nw = wend - wbase;
            for (int w = t; w < HPASS; w += 512) lds[w] = 0u;
            __syncthreads();
            int vlo = wbase * 2, vhi = wend * 2;
            for (int e = e0 + t; e < e1; e += 512) {
                int v = ecol[e];
                if (v >= vlo && v < vhi)
                    atomicAdd(&lds[(v >> 1) - wbase], (v & 1) ? 0x10000u : 1u);
            }
            __syncthreads();
            for (int w = t; w < nw; w += 512) partial[wbase + w] = lds[w];
            __syncthreads();
        }
    } else {
        int bb = b - HG;
        for (int i = t; i < NBK; i += 512) lds[i] = 0u;
        __syncthreads();
        int e0 = bb * EPB;
        for (int i = t; i < EPB; i += 512) atomicAdd(&lds[((unsigned)erow[e0 + i]) >> 8], 1u);
        __syncthreads();
        for (int i = t; i < NBK; i += 512) cnt[bb * NBK + i] = lds[i];
    }
}

// ================ P2: hist reduce -> dinv (blocks 0..97) + bucket scan/offsets (block 98) ================
__global__ __launch_bounds__(256) void k_p2(const unsigned* __restrict__ Pcol,
                                            float* __restrict__ dinv,
                                            const unsigned* __restrict__ cnt,
                                            unsigned* __restrict__ off,
                                            unsigned* __restrict__ bstart) {
    int t = threadIdx.x;
    if (blockIdx.x < 98) {
        int w = blockIdx.x * 256 + t;
        if (w >= HW) return;
        unsigned sc = 0;
        for (int b = 0; b < HG; b++) sc += Pcol[(size_t)b * HW + w];
        dinv[2 * w] = rsqrtf((float)((sc & 0xffffu) + 1u));
        dinv[2 * w + 1] = rsqrtf((float)((sc >> 16) + 1u));
    } else {
        __shared__ unsigned s[256];
        unsigned tot = 0;
        if (t < NBK) for (int b = 0; b < PB; b++) tot += cnt[b * NBK + t];
        s[t] = tot;
        __syncthreads();
        for (int o = 1; o < 256; o <<= 1) {
            unsigned x = (t >= o) ? s[t - o] : 0u;
            __syncthreads();
            s[t] += x;
            __syncthreads();
        }
        unsigned base = s[t] - tot;
        if (t < NBK) bstart[t] = base;
        if (t == NBK - 1) bstart[NBK] = base + tot;
        if (t < NBK) {
            unsigned run = base;
            for (int b = 0; b < PB; b++) { off[b * NBK + t] = run; run += cnt[b * NBK + t]; }
        }
    }
}

// ================ P3: edge scatter into buckets (blocks 0..PB) + input prep (rest) ================
__global__ __launch_bounds__(256) void k_p3(const int* __restrict__ erow,
                                            const int* __restrict__ ecol,
                                            const unsigned* __restrict__ off,
                                            int2* __restrict__ ebuf,
                                            const float* __restrict__ x,
                                            const float* __restrict__ dinv,
                                            uchar* __restrict__ xs8,
                                            const float* __restrict__ W1,
                                            const float* __restrict__ W2,
                                            const float* __restrict__ W3,
                                            ushort* __restrict__ Wt1,
                                            ushort* __restrict__ Wt2,
                                            ushort* __restrict__ Wt3) {
    int t = threadIdx.x, b = blockIdx.x;
    if (b < PB) {
        __shared__ unsigned c[NBK];
        for (int i = t; i < NBK; i += 256) c[i] = off[b * NBK + i];
        __syncthreads();
        int e0 = b * EPB;
        for (int i = t; i < EPB; i += 256) {
            int r = erow[e0 + i], cc = ecol[e0 + i];
            unsigned p = atomicAdd(&c[((unsigned)r) >> 8], 1u);
            ebuf[p] = make_int2(r, cc);
        }
    } else if (b < PB + 6250) {
        int i = (b - PB) * 256 + t;   // over N*128/4 = 1.6M exactly
        int row = i >> 5;
        float d = dinv[row];
        float4 v = ((const float4*)x)[i];
        int p = fp8_enc_lo(v.x * d, v.y * d, 0);
        p = fp8_enc_hi(v.z * d, v.w * d, p);
        ((int*)xs8)[i] = p;
    } else {
        int i = (b - PB - 6250) * 256 + t;
        if (i < 128 * 256) { int k = i / 256, n = i % 256; Wt1[n * 128 + k] = f2bf(W1[i]); }
        if (i < 256 * 256) { int k = i / 256, n = i % 256; Wt2[n * 256 + k] = f2bf(W2[i]); }
        if (i < 48 * 256)  { int n = i / 256, k = i % 256;
                             Wt3[i] = (n < OUT_DIM) ? f2bf(W3[k * OUT_DIM + n]) : (ushort)0; }
    }
}

// ================ P4: per-bucket row counts -> rowptr -> colidx fill ================
__global__ __launch_bounds__(256) void k_part4(const int2* __restrict__ ebuf,
                                               const unsigned* __restrict__ bstart,
                                               unsigned* __restrict__ rowptr,
                                               int* __restrict__ colidx) {
    __shared__ unsigned rc[256], cur[256], s[256];
    int t = threadIdx.x, b = blockIdx.x;
    unsigned ebase = bstart[b], ecnt = bstart[b + 1] - ebase;
    rc[t] = 0u;
    __syncthreads();
    for (unsigned i = t; i < ecnt; i += 256) atomicAdd(&rc[ebuf[ebase + i].x & 255], 1u);
    __syncthreads();
    unsigned v = rc[t];
    s[t] = v;
    __syncthreads();
    for (int o = 1; o < 256; o <<= 1) {
        unsigned x = (t >= o) ? s[t - o] : 0u;
        __syncthreads();
        s[t] += x;
        __syncthreads();
    }
    unsigned excl = s[t] - v;
    int row = (b << 8) + t;
    if (row < NN) rowptr[row] = ebase + excl;
    cur[t] = ebase + excl;
    if (b == 0 && t == 0) rowptr[NN] = NE;
    __syncthreads();
    for (unsigned i = t; i < ecnt; i += 256) {
        int2 e = ebuf[ebase + i];
        unsigned p = atomicAdd(&cur[e.x & 255], 1u);
        colidx[p] = e.y;
    }
}

// ================ layer-1 aggregation on fp8 features (128-dim, unroll-8) ================
__global__ __launch_bounds__(64) void k_agg_x(const uchar* __restrict__ xs8,
                                              const unsigned* __restrict__ rowptr,
                                              const int* __restrict__ colidx,
                                              const float* __restrict__ dinv,
                                              ushort* __restrict__ Xa) {
    int r = blockIdx.x;
    int t = threadIdx.x;  // 64 lanes x 2 fp8 cols
    const ushort* Xv = (const ushort*)xs8;
    f32x2 sf = fp8_dec_lo((int)Xv[(size_t)r * 64 + t]);
    float a0 = sf[0], a1 = sf[1];
    unsigned e0 = rowptr[r], e1 = rowptr[r + 1];
    unsigned e = e0;
    for (; e + 8 <= e1; e += 8) {
        int v0 = Xv[(size_t)colidx[e] * 64 + t];
        int v1 = Xv[(size_t)colidx[e + 1] * 64 + t];
        int v2 = Xv[(size_t)colidx[e + 2] * 64 + t];
        int v3 = Xv[(size_t)colidx[e + 3] * 64 + t];
        int v4 = Xv[(size_t)colidx[e + 4] * 64 + t];
        int v5 = Xv[(size_t)colidx[e + 5] * 64 + t];
        int v6 = Xv[(size_t)colidx[e + 6] * 64 + t];
        int v7 = Xv[(size_t)colidx[e + 7] * 64 + t];
        f32x2 f0 = fp8_dec_lo(v0), f1 = fp8_dec_lo(v1);
        f32x2 f2 = fp8_dec_lo(v2), f3 = fp8_dec_lo(v3);
        f32x2 f4 = fp8_dec_lo(v4), f5 = fp8_dec_lo(v5);
        f32x2 f6 = fp8_dec_lo(v6), f7 = fp8_dec_lo(v7);
        a0 += f0[0] + f1[0] + f2[0] + f3[0] + f4[0] + f5[0] + f6[0] + f7[0];
        a1 += f0[1] + f1[1] + f2[1] + f3[1] + f4[1] + f5[1] + f6[1] + f7[1];
    }
    for (; e < e1; e++) {
        f32x2 f = fp8_dec_lo((int)Xv[(size_t)colidx[e] * 64 + t]);
        a0 += f[0]; a1 += f[1];
    }
    float dr = dinv[r];
    ((unsigned*)Xa)[(size_t)r * 64 + t] = (unsigned)f2bf(dr * a0) | ((unsigned)f2bf(dr * a1) << 16);
}

// ================ MFMA GEMM 1 (+fused BN1 column stats): H16 = Xa @ Wt1^T ================
template <int K>
__global__ __launch_bounds__(256) void k_gemm1(const ushort* __restrict__ A,
                                               const ushort* __restrict__ Bt,
                                               ushort* __restrict__ H16,
                                               float* __restrict__ bnacc) {
    constexpr int BK = 32;
    constexpr int LD = 40;
    __shared__ ushort sA[64 * LD];
    __shared__ ushort sB[128 * LD];
    int t = threadIdx.x;
    int wave = t >> 6, lane = t & 63;
    int quad = lane >> 4, m15 = lane & 15;
    long r0 = (long)blockIdx.x * 64;
    int n0 = blockIdx.y * 128;

    f32x4 acc[8];
#pragma unroll
    for (int i = 0; i < 8; i++) { acc[i][0] = 0.f; acc[i][1] = 0.f; acc[i][2] = 0.f; acc[i][3] = 0.f; }

    for (int k0 = 0; k0 < K; k0 += BK) {
        {
            int row = t >> 2, seg = (t & 3) * 8;
            long gr = r0 + row;
            uint4 v = make_uint4(0, 0, 0, 0);
            if (gr < NN) v = *(const uint4*)(A + gr * K + k0 + seg);
            *(uint4*)(sA + row * LD + seg) = v;
        }
        {
            int n = t >> 1, seg = (t & 1) * 16;
            const uint4* src = (const uint4*)(Bt + (long)(n0 + n) * K + k0 + seg);
            uint4 b0 = src[0], b1 = src[1];
            *(uint4*)(sB + n * LD + seg) = b0;
            *(uint4*)(sB + n * LD + seg + 8) = b1;
        }
        __syncthreads();
        short8 a = *(const short8*)(sA + (wave * 16 + m15) * LD + quad * 8);
#pragma unroll
        for (int ct = 0; ct < 8; ct++) {
            short8 b = *(const short8*)(sB + (ct * 16 + m15) * LD + quad * 8);
            acc[ct] = __builtin_amdgcn_mfma_f32_16x16x32_bf16(a, b, acc[ct], 0, 0, 0);
        }
        __syncthreads();
    }
    long rowbase = r0 + wave * 16 + quad * 4;
#pragma unroll
    for (int ct = 0; ct < 8; ct++) {
        int col = n0 + ct * 16 + m15;
#pragma unroll
        for (int rg = 0; rg < 4; rg++) {
            long gr = rowbase + rg;
            if (gr < NN) H16[gr * 256 + col] = f2bf(acc[ct][rg]);
        }
    }
    // ---- fused BN1 column stats (conv1 output == acc; guard rows are exact zeros) ----
    float* ldsS = (float*)(void*)sA;   // 4 waves x 128 cols
    float* ldsQ = (float*)(void*)sB;
#pragma unroll
    for (int ct = 0; ct < 8; ct++) {
        float s = acc[ct][0] + acc[ct][1] + acc[ct][2] + acc[ct][3];
        float q = acc[ct][0] * acc[ct][0] + acc[ct][1] * acc[ct][1]
                + acc[ct][2] * acc[ct][2] + acc[ct][3] * acc[ct][3];
        s += __shfl_xor(s, 16, 64); q += __shfl_xor(q, 16, 64);
        s += __shfl_xor(s, 32, 64); q += __shfl_xor(q, 32, 64);
        if (quad == 0) {
            ldsS[wave * 128 + ct * 16 + m15] = s;
            ldsQ[wave * 128 + ct * 16 + m15] = q;
        }
    }
    __syncthreads();
    {
        int c = t & 127;
        int slice = blockIdx.x & 7;
        float v = (t < 128)
            ? ldsS[c] + ldsS[128 + c] + ldsS[256 + c] + ldsS[384 + c]
            : ldsQ[c] + ldsQ[128 + c] + ldsQ[256 + c] + ldsQ[384 + c];
        atomicAdd(&bnacc[slice * 512 + ((t < 128) ? 0 : 256) + n0 + c], v);
    }
}

// BN+ReLU stage of 8 bf16 cols from H16 row into LDS
__device__ __forceinline__ void bn_stage8(const ushort* __restrict__ Hrow, bool valid,
                                          const float* __restrict__ bn, int col0,
                                          ushort* __restrict__ dst) {
    uint4 hv = make_uint4(0, 0, 0, 0);
    if (valid) hv = *(const uint4*)(Hrow + col0);
    float f[8] = { bflo(hv.x), bfhi(hv.x), bflo(hv.y), bfhi(hv.y),
                   bflo(hv.z), bfhi(hv.z), bflo(hv.w), bfhi(hv.w) };
#pragma unroll
    for (int j = 0; j < 8; j++)
        dst[j] = f2bf(fmaxf(f[j] * bn[512 + col0 + j] + bn[768 + col0 + j], 0.f));
}

// ================ MFMA GEMM 2: Ys2(fp8) = fp8( dinv * (relu(bn(H16)) @ Wt2^T) ) ================
__global__ __launch_bounds__(256) void k_gemm2(const ushort* __restrict__ H16,
                                               const float* __restrict__ bn,
                                               const ushort* __restrict__ Bt,
                                               const float* __restrict__ dinv,
                                               uchar* __restrict__ Y8) {
    constexpr int K = 256, BK = 32, LD = 40;
    __shared__ ushort sA[64 * LD];
    __shared__ ushort sB[128 * LD];
    int t = threadIdx.x;
    int wave = t >> 6, lane = t & 63;
    int quad = lane >> 4, m15 = lane & 15;
    long r0 = (long)blockIdx.x * 64;
    int n0 = blockIdx.y * 128;

    f32x4 acc[8];
#pragma unroll
    for (int i = 0; i < 8; i++) { acc[i][0] = 0.f; acc[i][1] = 0.f; acc[i][2] = 0.f; acc[i][3] = 0.f; }

    for (int k0 = 0; k0 < K; k0 += BK) {
        {
            int row = t >> 2, seg = (t & 3) * 8;
            long gr = r0 + row;
            bn_stage8(H16 + gr * 256, gr < NN, bn, k0 + seg, sA + row * LD + seg);
        }
        {
            int n = t >> 1, seg = (t & 1) * 16;
            const uint4* src = (const uint4*)(Bt + (long)(n0 + n) * K + k0 + seg);
            uint4 b0 = src[0], b1 = src[1];
            *(uint4*)(sB + n * LD + seg) = b0;
            *(uint4*)(sB + n * LD + seg + 8) = b1;
        }
        __syncthreads();
        short8 a = *(const short8*)(sA + (wave * 16 + m15) * LD + quad * 8);
#pragma unroll
        for (int ct = 0; ct < 8; ct++) {
            short8 b = *(const short8*)(sB + (ct * 16 + m15) * LD + quad * 8);
            acc[ct] = __builtin_amdgcn_mfma_f32_16x16x32_bf16(a, b, acc[ct], 0, 0, 0);
        }
        __syncthreads();
    }
    long rowbase = r0 + wave * 16 + quad * 4;
    float dv[4];
#pragma unroll
    for (int rg = 0; rg < 4; rg++) dv[rg] = (rowbase + rg < NN) ? dinv[rowbase + rg] : 0.f;
#pragma unroll
    for (int ct = 0; ct < 8; ct++) {
        int col = n0 + ct * 16 + m15;
#pragma unroll
        for (int rg = 0; rg < 4; rg++) {
            long gr = rowbase + rg;
            if (gr < NN) {
                int p = fp8_enc_lo(dv[rg] * acc[ct][rg], 0.f, 0);
                Y8[gr * 256 + col] = (uchar)(p & 0xff);
            }
        }
    }
}

// ================ MFMA GEMM 3: Ys3 (stride 64, bf16) = dinv * (relu(bn(H16)) @ Wt3^T) ================
__global__ __launch_bounds__(256) void k_gemm3(const ushort* __restrict__ H16,
                                               const float* __restrict__ bn,
                                               const ushort* __restrict__ Wt3,
                                               const float* __restrict__ dinv,
                                               ushort* __restrict__ Y) {
    constexpr int LD = 264;
    __shared__ ushort sA[64 * LD];
    __shared__ ushort sB[48 * LD];
    int t = threadIdx.x;
    int wave = t >> 6, lane = t & 63;
    int quad = lane >> 4, m15 = lane & 15;
    long r0 = (long)blockIdx.x * 64;

    for (int idx = t; idx < 48 * 16; idx += 256) {
        int n = idx >> 4, s = (idx & 15) * 16;
        const uint4* src = (const uint4*)(Wt3 + n * 256 + s);
        *(uint4*)(sB + n * LD + s) = src[0];
        *(uint4*)(sB + n * LD + s + 8) = src[1];
    }
    {
        int row = t >> 2;
        long gr = r0 + row;
#pragma unroll
        for (int s8 = 0; s8 < 8; s8++) {
            int seg = s8 * 32 + (t & 3) * 8;
            bn_stage8(H16 + gr * 256, gr < NN, bn, seg, sA + row * LD + seg);
        }
    }
    __syncthreads();

    f32x4 acc[3];
#pragma unroll
    for (int i = 0; i < 3; i++) { acc[i][0] = 0.f; acc[i][1] = 0.f; acc[i][2] = 0.f; acc[i][3] = 0.f; }
#pragma unroll
    for (int k0 = 0; k0 < 256; k0 += 32) {
        short8 a = *(const short8*)(sA + (wave * 16 + m15) * LD + k0 + quad * 8);
#pragma unroll
        for (int ct = 0; ct < 3; ct++) {
            short8 b = *(const short8*)(sB + (ct * 16 + m15) * LD + k0 + quad * 8);
            acc[ct] = __builtin_amdgcn_mfma_f32_16x16x32_bf16(a, b, acc[ct], 0, 0, 0);
        }
    }
    long rowbase = r0 + wave * 16 + quad * 4;
#pragma unroll
    for (int ct = 0; ct < 3; ct++) {
        int col = ct * 16 + m15;
#pragma unroll
        for (int rg = 0; rg < 4; rg++) {
            long gr = rowbase + rg;
            if (gr < NN) Y[gr * 64 + col] = f2bf(dinv[gr] * acc[ct][rg]);
        }
    }
}

// ================ layer-2 aggregation: fp8 gather -> bf16 H16 (unroll-8) ================
__global__ __launch_bounds__(64) void k_agg_hid(const uchar* __restrict__ Y8,
                                                const unsigned* __restrict__ rowptr,
                                                const int* __restrict__ colidx,
                                                const float* __restrict__ dinv,
                                                ushort* __restrict__ H16) {
    int r = blockIdx.x;
    int t = threadIdx.x;  // 64 lanes x 4 fp8 cols
    const int* Yv = (const int*)Y8;
    int y = Yv[(size_t)r * 64 + t];
    f32x2 yl = fp8_dec_lo(y), yh = fp8_dec_hi(y);
    float a0 = yl[0], a1 = yl[1], a2 = yh[0], a3 = yh[1];
    unsigned e0 = rowptr[r], e1 = rowptr[r + 1];
    unsigned e = e0;
    for (; e + 8 <= e1; e += 8) {
        int v0 = Yv[(size_t)colidx[e] * 64 + t];
        int v1 = Yv[(size_t)colidx[e + 1] * 64 + t];
        int v2 = Yv[(size_t)colidx[e + 2] * 64 + t];
        int v3 = Yv[(size_t)colidx[e + 3] * 64 + t];
        int v4 = Yv[(size_t)colidx[e + 4] * 64 + t];
        int v5 = Yv[(size_t)colidx[e + 5] * 64 + t];
        int v6 = Yv[(size_t)colidx[e + 6] * 64 + t];
        int v7 = Yv[(size_t)colidx[e + 7] * 64 + t];
        f32x2 l0 = fp8_dec_lo(v0), h0 = fp8_dec_hi(v0);
        f32x2 l1 = fp8_dec_lo(v1), h1 = fp8_dec_hi(v1);
        f32x2 l2 = fp8_dec_lo(v2), h2 = fp8_dec_hi(v2);
        f32x2 l3 = fp8_dec_lo(v3), h3 = fp8_dec_hi(v3);
        f32x2 l4 = fp8_dec_lo(v4), h4 = fp8_dec_hi(v4);
        f32x2 l5 = fp8_dec_lo(v5), h5 = fp8_dec_hi(v5);
        f32x2 l6 = fp8_dec_lo(v6), h6 = fp8_dec_hi(v6);
        f32x2 l7 = fp8_dec_lo(v7), h7 = fp8_dec_hi(v7);
        a0 += l0[0] + l1[0] + l2[0] + l3[0] + l4[0] + l5[0] + l6[0] + l7[0];
        a1 += l0[1] + l1[1] + l2[1] + l3[1] + l4[1] + l5[1] + l6[1] + l7[1];
        a2 += h0[0] + h1[0] + h2[0] + h3[0] + h4[0] + h5[0] + h6[0] + h7[0];
        a3 += h0[1] + h1[1] + h2[1] + h3[1] + h4[1] + h5[1] + h6[1] + h7[1];
    }
    for (; e < e1; e++) {
        int v = Yv[(size_t)colidx[e] * 64 + t];
        f32x2 l = fp8_dec_lo(v), h = fp8_dec_hi(v);
        a0 += l[0]; a1 += l[1]; a2 += h[0]; a3 += h[1];
    }
    float dr = dinv[r];
    uint2 o;
    o.x = (unsigned)f2bf(dr * a0) | ((unsigned)f2bf(dr * a1) << 16);
    o.y = (unsigned)f2bf(dr * a2) | ((unsigned)f2bf(dr * a3) << 16);
    ((uint2*)H16)[(size_t)r * 64 + t] = o;
}

// ================ layer-3 aggregation + bias + log_softmax ================
__global__ __launch_bounds__(64) void k_agg_lsm(const ushort* __restrict__ Y,
                                                const unsigned* __restrict__ rowptr,
                                                const int* __restrict__ colidx,
                                                const float* __restrict__ dinv,
                                                const float* __restrict__ b3,
                                                float* __restrict__ out) {
    int r = blockIdx.x;
    int t = threadIdx.x;
    bool act = t < OUT_DIM;
    float acc = act ? bflo((unsigned)Y[(size_t)r * 64 + t]) : 0.f;
    unsigned e0 = rowptr[r], e1 = rowptr[r + 1];
    unsigned e = e0;
    for (; e + 4 <= e1; e += 4) {
        int c0 = colidx[e], c1 = colidx[e + 1], c2 = colidx[e + 2], c3 = colidx[e + 3];
        if (act) {
            acc += bflo((unsigned)Y[(size_t)c0 * 64 + t]) + bflo((unsigned)Y[(size_t)c1 * 64 + t])
                 + bflo((unsigned)Y[(size_t)c2 * 64 + t]) + bflo((unsigned)Y[(size_t)c3 * 64 + t]);
        }
    }
    for (; e < e1; e++) {
        if (act) acc += bflo((unsigned)Y[(size_t)colidx[e] * 64 + t]);
    }
    float o = act ? (dinv[r] * acc + b3[t]) : 0.f;
    float m = act ? o : -1e30f;
#pragma unroll
    for (int d = 1; d < 64; d <<= 1) m = fmaxf(m, __shfl_xor(m, d, 64));
    float ex = act ? expf(o - m) : 0.f;
#pragma unroll
    for (int d = 1; d < 64; d <<= 1) ex += __shfl_xor(ex, d, 64);
    float ls = logf(ex) + m;
    if (act) out[(size_t)r * OUT_DIM + t] = o - ls;
}

// ================ fast BN stats for layer 2 (uint4 loads, LDS reduce, slice atomics) ================
__global__ __launch_bounds__(256) void k_bn_stats2(const ushort* __restrict__ H16,
                                                   float* __restrict__ bnacc) {
    __shared__ float ls[512];
    int t = threadIdx.x;
    ls[t] = 0.f; ls[t + 256] = 0.f;
    __syncthreads();
    int colb = (t & 31) * 8;
    float s[8], q[8];
#pragma unroll
    for (int j = 0; j < 8; j++) { s[j] = 0.f; q[j] = 0.f; }
    for (int rb = blockIdx.x * 8 + (t >> 5); rb < NN; rb += gridDim.x * 8) {
        uint4 v = *(const uint4*)(H16 + (size_t)rb * 256 + colb);
        float f[8] = { bflo(v.x), bfhi(v.x), bflo(v.y), bfhi(v.y),
                       bflo(v.z), bfhi(v.z), bflo(v.w), bfhi(v.w) };
#pragma unroll
        for (int j = 0; j < 8; j++) { s[j] += f[j]; q[j] += f[j] * f[j]; }
    }
#pragma unroll
    for (int j = 0; j < 8; j++) {
        atomicAdd(&ls[colb + j], s[j]);
        atomicAdd(&ls[256 + colb + j], q[j]);
    }
    __syncthreads();
    int slice = blockIdx.x & 7;
    atomicAdd(&bnacc[slice * 512 + t], ls[t]);
    atomicAdd(&bnacc[slice * 512 + 256 + t], ls[t + 256]);
}

// ================ BN finalize: reduce 8 slices -> scale/shift ================
__global__ __launch_bounds__(256) void k_bn_final(const float* __restrict__ bnacc,
                                                  const float* __restrict__ gamma,
                                                  const float* __restrict__ beta,
                                                  float* __restrict__ bn) {
    int t = threadIdx.x;
    float s = 0.f, sq = 0.f;
#pragma unroll
    for (int sl = 0; sl < 8; sl++) {
        s += bnacc[sl * 512 + t];
        sq += bnacc[sl * 512 + 256 + t];
    }
    float mu = s * (1.f / NN);
    float var = sq * (1.f / NN) - mu * mu;
    float rstd = rsqrtf(var + BN_EPS);
    float g = gamma[t] * rstd;
    bn[512 + t] = g;
    bn[768 + t] = beta[t] - mu * g;
}

// ================ launch ================

extern "C" void kernel_launch(void* const* d_in, const int* in_sizes, int n_in,
                              void* d_out, int out_size, void* d_ws, size_t ws_size,
                              hipStream_t stream) {
    const float* x     = (const float*)d_in[0];
    const int*   erow  = (const int*)d_in[1];
    const int*   ecol  = ((const int*)d_in[1]) + NE;
    const float* W1    = (const float*)d_in[2];
    const float* W2    = (const float*)d_in[4];
    const float* W3    = (const float*)d_in[6];
    const float* b3    = (const float*)d_in[7];
    const float* gamma = (const float*)d_in[8];
    const float* beta  = (const float*)d_in[9];
    float* out = (float*)d_out;

    char* ws = (char*)d_ws;
    size_t off = 0;
    auto alloc = [&](size_t bytes) -> void* {
        void* p = ws + off;
        off = (off + bytes + 255) & ~(size_t)255;
        return p;
    };
    float*    dinv     = (float*)alloc(NN * 4);
    unsigned* rowptr   = (unsigned*)alloc((NN + 1) * 4);
    int*      colidx   = (int*)alloc((size_t)NE * 4);
    float*    bn       = (float*)alloc(1024 * 4);
    float*    bnacc    = (float*)alloc(8 * 512 * 4);
    unsigned* cnt      = (unsigned*)alloc((size_t)PB * NBK * 4);
    unsigned* boff     = (unsigned*)alloc((size_t)PB * NBK * 4);
    unsigned* bstart   = (unsigned*)alloc((NBK + 1) * 4);
    ushort*   Wt1      = (ushort*)alloc(128 * 256 * 2);
    ushort*   Wt2      = (ushort*)alloc(256 * 256 * 2);
    ushort*   Wt3      = (ushort*)alloc(48 * 256 * 2);
    uchar*    xs8      = (uchar*)alloc((size_t)NN * IN_DIM);       // fp8 dinv-scaled x
    ushort*   Xa       = (ushort*)alloc((size_t)NN * IN_DIM * 2);  // aggregated x, bf16
    ushort*   H16      = (ushort*)alloc((size_t)NN * HID * 2);     // conv output, bf16
    uchar*    Ys2      = (uchar*)alloc((size_t)NN * HID);          // fp8 layer-2 transform
    ushort*   Ys3      = (ushort*)alloc((size_t)NN * 64 * 2);      // bf16 layer-3 transform

    // aliases into H16 (25.6 MB), dead before gemm1 writes H16:
    unsigned* Pcol = (unsigned*)H16;                                   // 12.8 MB
    int2*     ebuf = (int2*)((char*)H16 + (size_t)13 * 1024 * 1024);   // 6.4 MB

    // --- preprocessing (merged) ---
    k_p1<<<HG + PB, 512, 0, stream>>>(erow, ecol, Pcol, cnt);
    k_p2<<<99, 256, 0, stream>>>(Pcol, dinv, cnt, boff, bstart);
    k_p3<<<PB + 6250 + 256, 256, 0, stream>>>(erow, ecol, boff, ebuf,
                                              x, dinv, xs8, W1, W2, W3, Wt1, Wt2, Wt3);
    k_part4<<<NBK, 256, 0, stream>>>(ebuf, bstart, rowptr, colidx);
    hipMemsetAsync(bnacc, 0, 8 * 512 * 4, stream);

    dim3 ggrid((NN + 63) / 64, 2);

    // --- layer 1: aggregate-first (fp8 gather), transform + fused BN1 stats ---
    k_agg_x<<<NN, 64, 0, stream>>>(xs8, rowptr, colidx, dinv, Xa);
    k_gemm1<IN_DIM><<<ggrid, 256, 0, stream>>>(Xa, Wt1, H16, bnacc);
    k_bn_final<<<1, 256, 0, stream>>>(bnacc, gamma, beta, bn);

    // --- layer 2: BN fused into GEMM staging; fp8 output table ---
    k_gemm2<<<ggrid, 256, 0, stream>>>(H16, bn, Wt2, dinv, Ys2);
    k_agg_hid<<<NN, 64, 0, stream>>>(Ys2, rowptr, colidx, dinv, H16);
    hipMemsetAsync(bnacc, 0, 8 * 512 * 4, stream);
    k_bn_stats2<<<1024, 256, 0, stream>>>(H16, bnacc);
    k_bn_final<<<1, 256, 0, stream>>>(bnacc, gamma, beta, bn);

    // --- layer 3 ---
    k_gemm3<<<(NN + 63) / 64, 256, 0, stream>>>(H16, bn, Wt3, dinv, Ys3);
    k_agg_lsm<<<NN, 64, 0, stream>>>(Ys3, rowptr, colidx, dinv, b3, out);
}